// Round 1
// baseline (5169.641 us; speedup 1.0000x reference)
//
#include <hip/hip_runtime.h>

#define T_LEN 8000
#define NTPB 125            // time tiles per batch (8000/64)
#define BATCH 2
#define RCH 128
#define SCH 128
#define CCH 80
#define ICH 256
#define OCH 256
#define TILE 64
#define NLAYER 30
#define INV_SQRT2 0.70710678118f

__device__ __forceinline__ void tile_decode(int& b, int& t0) {
    int tile = blockIdx.x;
    b = tile / NTPB;
    t0 = (tile - b * NTPB) * TILE;
}

// ---------------- weight transposes: W[l][o][i] -> wT[l][i][o] ----------------
__global__ void k_transpose(const float* __restrict__ src, float* __restrict__ dst,
                            int L, int O, int I)
{
    int idx = blockIdx.x * blockDim.x + threadIdx.x;
    int tot = L * O * I;
    if (idx >= tot) return;
    int l = idx / (O * I);
    int r = idx - l * O * I;
    int o = r / I;
    int i = r - o * I;
    dst[(l * I + i) * O + o] = src[idx];
}

// dil_w [30][128][128][2] -> tap0 / tap1 transposed arenas
__global__ void k_transpose_dil(const float* __restrict__ src,
                                float* __restrict__ d0, float* __restrict__ d1)
{
    int idx = blockIdx.x * blockDim.x + threadIdx.x;
    const int tot = NLAYER * RCH * RCH;
    if (idx >= tot) return;
    int l = idx / (RCH * RCH);
    int r = idx - l * RCH * RCH;
    int o = r / RCH;
    int i = r - o * RCH;
    int dsti = (l * RCH + i) * RCH + o;
    d0[dsti] = src[idx * 2 + 0];
    d1[dsti] = src[idx * 2 + 1];
}

// ---------------- input 1x1 conv: h0 = input_w @ x + b; skip = 0 ----------------
__global__ __launch_bounds__(256) void k_input(
    const float* __restrict__ x, const float* __restrict__ inT,
    const float* __restrict__ ib, float* __restrict__ h0, float* __restrict__ skip)
{
    __shared__ float s_x[RCH][TILE];
    int b, t0; tile_decode(b, t0);
    const int lane = threadIdx.x & 63;
    const int w = threadIdx.x >> 6;
    const int cw = __builtin_amdgcn_readfirstlane(w);
    const int c0 = cw * 32;
    float acc[32];
#pragma unroll
    for (int j = 0; j < 32; ++j) acc[j] = ib[c0 + j];
    const float* xb = x + (size_t)b * ICH * T_LEN;
    for (int half = 0; half < 2; ++half) {
        __syncthreads();
        for (int k = w; k < RCH; k += 4)
            s_x[k][lane] = xb[(half * RCH + k) * T_LEN + t0 + lane];
        __syncthreads();
        const float* wT = inT + half * RCH * RCH;
        for (int k = 0; k < RCH; ++k) {
            float xv = s_x[k][lane];
            const float* wr = wT + k * RCH + c0;
#pragma unroll
            for (int j = 0; j < 32; ++j) acc[j] = fmaf(wr[j], xv, acc[j]);
        }
    }
    size_t base = (size_t)b * RCH * T_LEN + t0 + lane;
#pragma unroll
    for (int j = 0; j < 32; ++j) {
        h0[base + (size_t)(c0 + j) * T_LEN] = acc[j];
        skip[base + (size_t)(c0 + j) * T_LEN] = 0.f;
    }
}

// ---------------- layer kernel A: out = tanh(a) * sigmoid(g) ----------------
__global__ __launch_bounds__(256) void k_layerA(
    const float* __restrict__ h, const float* __restrict__ cond,
    const float* __restrict__ w0T, const float* __restrict__ w1T,
    const float* __restrict__ wgT, const float* __restrict__ wcT,
    const float* __restrict__ wcgT,
    const float* __restrict__ db, const float* __restrict__ cb,
    const float* __restrict__ gb, const float* __restrict__ cgb,
    float* __restrict__ outb, int dil)
{
    __shared__ float s_h[RCH][TILE];   // h[t-d], later reused for h[t]
    __shared__ float s_c[CCH][TILE];   // condition tile
    int b, t0; tile_decode(b, t0);
    const int lane = threadIdx.x & 63;
    const int w = threadIdx.x >> 6;
    const float* hb  = h    + (size_t)b * RCH * T_LEN;
    const float* cnb = cond + (size_t)b * CCH * T_LEN;
    {
        int ts = t0 - dil + lane;
        for (int k = w; k < RCH; k += 4)
            s_h[k][lane] = (ts >= 0) ? hb[k * T_LEN + ts] : 0.f;
        for (int k = w; k < CCH; k += 4)
            s_c[k][lane] = cnb[k * T_LEN + t0 + lane];
    }
    const int cw = __builtin_amdgcn_readfirstlane(w);
    const int c0 = cw * 32;
    float a[32], g[32];
#pragma unroll
    for (int j = 0; j < 32; ++j) {
        a[j] = db[c0 + j] + cb[c0 + j];
        g[j] = gb[c0 + j] + cgb[c0 + j];
    }
    __syncthreads();
    // segment 1: a += Wd0 @ h[t-d]
    for (int k = 0; k < RCH; ++k) {
        float xv = s_h[k][lane];
        const float* wr = w0T + k * RCH + c0;
#pragma unroll
        for (int j = 0; j < 32; ++j) a[j] = fmaf(wr[j], xv, a[j]);
    }
    // segment 3: a += Wc @ cond ; g += Wcg @ cond
    for (int k = 0; k < CCH; ++k) {
        float xv = s_c[k][lane];
        const float* wr  = wcT  + k * RCH + c0;
        const float* wr2 = wcgT + k * RCH + c0;
#pragma unroll
        for (int j = 0; j < 32; ++j) {
            a[j] = fmaf(wr[j],  xv, a[j]);
            g[j] = fmaf(wr2[j], xv, g[j]);
        }
    }
    __syncthreads();
    // restage h[t] into s_h
    for (int k = w; k < RCH; k += 4)
        s_h[k][lane] = hb[k * T_LEN + t0 + lane];
    __syncthreads();
    // segment 2: a += Wd1 @ h[t] ; g += Wg @ h[t]
    for (int k = 0; k < RCH; ++k) {
        float xv = s_h[k][lane];
        const float* wr  = w1T + k * RCH + c0;
        const float* wr2 = wgT + k * RCH + c0;
#pragma unroll
        for (int j = 0; j < 32; ++j) {
            a[j] = fmaf(wr[j],  xv, a[j]);
            g[j] = fmaf(wr2[j], xv, g[j]);
        }
    }
    float* ob = outb + (size_t)b * RCH * T_LEN + t0 + lane;
#pragma unroll
    for (int j = 0; j < 32; ++j) {
        float av = a[j], gv = g[j];
        float e  = __expf(-2.f * fabsf(av));
        float th = (1.f - e) * __builtin_amdgcn_rcpf(1.f + e);
        th = (av < 0.f) ? -th : th;
        float sg = __builtin_amdgcn_rcpf(1.f + __expf(-gv));
        ob[(size_t)(c0 + j) * T_LEN] = th * sg;
    }
}

// ---------------- layer kernel B: h_new = (h + Wr@out + rb)*c ; skip += Ws@out + sb ----------------
__global__ __launch_bounds__(256) void k_layerB(
    const float* __restrict__ h, const float* __restrict__ outb,
    const float* __restrict__ wrT, const float* __restrict__ wsT,
    const float* __restrict__ rb, const float* __restrict__ sb,
    float* __restrict__ hnew, float* __restrict__ skip)
{
    __shared__ float s_x[RCH][TILE];
    int b, t0; tile_decode(b, t0);
    const int lane = threadIdx.x & 63;
    const int w = threadIdx.x >> 6;
    const float* ob = outb + (size_t)b * RCH * T_LEN;
    for (int k = w; k < RCH; k += 4)
        s_x[k][lane] = ob[k * T_LEN + t0 + lane];
    const int cw = __builtin_amdgcn_readfirstlane(w);
    const int c0 = cw * 32;
    float r[32], s[32];
#pragma unroll
    for (int j = 0; j < 32; ++j) { r[j] = rb[c0 + j]; s[j] = sb[c0 + j]; }
    __syncthreads();
    for (int k = 0; k < RCH; ++k) {
        float xv = s_x[k][lane];
        const float* w1 = wrT + k * RCH + c0;
        const float* w2 = wsT + k * RCH + c0;
#pragma unroll
        for (int j = 0; j < 32; ++j) {
            r[j] = fmaf(w1[j], xv, r[j]);
            s[j] = fmaf(w2[j], xv, s[j]);
        }
    }
    const size_t base = (size_t)b * RCH * T_LEN + t0 + lane;
#pragma unroll
    for (int j = 0; j < 32; ++j) {
        size_t idx = base + (size_t)(c0 + j) * T_LEN;
        hnew[idx] = (h[idx] + r[j]) * INV_SQRT2;
        skip[idx] += s[j];
    }
}

// ---------------- output head: out = out2 @ relu(out1 @ skip + b1) + b2 ----------------
__global__ __launch_bounds__(256) void k_output(
    const float* __restrict__ skip, const float* __restrict__ w1T,
    const float* __restrict__ b1, const float* __restrict__ w2T,
    const float* __restrict__ b2, float* __restrict__ out)
{
    __shared__ float s_x[SCH][TILE];
    int b, t0; tile_decode(b, t0);
    const int lane = threadIdx.x & 63;
    const int w = threadIdx.x >> 6;
    const int cw = __builtin_amdgcn_readfirstlane(w);
    const float* sk = skip + (size_t)b * SCH * T_LEN;
    for (int k = w; k < SCH; k += 4)
        s_x[k][lane] = sk[k * T_LEN + t0 + lane];
    __syncthreads();
    const int c0 = cw * 32;
    float y[32];
#pragma unroll
    for (int j = 0; j < 32; ++j) y[j] = b1[c0 + j];
    for (int k = 0; k < SCH; ++k) {
        float xv = s_x[k][lane];
        const float* wr = w1T + k * SCH + c0;
#pragma unroll
        for (int j = 0; j < 32; ++j) y[j] = fmaf(wr[j], xv, y[j]);
    }
#pragma unroll
    for (int j = 0; j < 32; ++j) y[j] = fmaxf(y[j], 0.f);
    __syncthreads();
#pragma unroll
    for (int j = 0; j < 32; ++j) s_x[c0 + j][lane] = y[j];
    __syncthreads();
    const int c1 = cw * 64;
    float o[64];
#pragma unroll
    for (int j = 0; j < 64; ++j) o[j] = b2[c1 + j];
    for (int k = 0; k < SCH; ++k) {
        float xv = s_x[k][lane];
        const float* wr = w2T + k * OCH + c1;
#pragma unroll
        for (int j = 0; j < 64; ++j) o[j] = fmaf(wr[j], xv, o[j]);
    }
    float* outp = out + (size_t)b * OCH * T_LEN + t0 + lane;
#pragma unroll
    for (int j = 0; j < 64; ++j) outp[(size_t)(c1 + j) * T_LEN] = o[j];
}

extern "C" void kernel_launch(void* const* d_in, const int* in_sizes, int n_in,
                              void* d_out, int out_size, void* d_ws, size_t ws_size,
                              hipStream_t stream)
{
    const float* x        = (const float*)d_in[0];
    const float* cond     = (const float*)d_in[1];
    const float* input_w  = (const float*)d_in[2];
    const float* input_b  = (const float*)d_in[3];
    const float* dil_w    = (const float*)d_in[4];
    const float* dil_b    = (const float*)d_in[5];
    const float* gate_w   = (const float*)d_in[6];
    const float* gate_b   = (const float*)d_in[7];
    const float* cond_w   = (const float*)d_in[8];
    const float* cond_b   = (const float*)d_in[9];
    const float* condg_w  = (const float*)d_in[10];
    const float* condg_b  = (const float*)d_in[11];
    const float* res_w    = (const float*)d_in[12];
    const float* res_b    = (const float*)d_in[13];
    const float* skip_w   = (const float*)d_in[14];
    const float* skip_b   = (const float*)d_in[15];
    const float* out1_w   = (const float*)d_in[16];
    const float* out1_b   = (const float*)d_in[17];
    const float* out2_w   = (const float*)d_in[18];
    const float* out2_b   = (const float*)d_in[19];
    float* outp = (float*)d_out;
    float* ws = (float*)d_ws;

    const size_t ACT = (size_t)BATCH * RCH * T_LEN;   // 2,048,000 floats
    float* h0   = ws;
    float* h1   = h0   + ACT;
    float* ob   = h1   + ACT;
    float* skip = ob   + ACT;
    float* wd0T = skip + ACT;
    float* wd1T = wd0T + (size_t)NLAYER * RCH * RCH;
    float* wgT  = wd1T + (size_t)NLAYER * RCH * RCH;
    float* wcT  = wgT  + (size_t)NLAYER * RCH * RCH;
    float* wcgT = wcT  + (size_t)NLAYER * CCH * RCH;
    float* wrT  = wcgT + (size_t)NLAYER * CCH * RCH;
    float* wsT  = wrT  + (size_t)NLAYER * RCH * RCH;
    float* inT  = wsT  + (size_t)NLAYER * RCH * RCH;
    float* o1T  = inT  + (size_t)ICH * RCH;
    float* o2T  = o1T  + (size_t)SCH * SCH;

    auto nb = [](int n) { return dim3((n + 255) / 256); };
    k_transpose_dil<<<nb(NLAYER*RCH*RCH), 256, 0, stream>>>(dil_w, wd0T, wd1T);
    k_transpose<<<nb(NLAYER*RCH*RCH), 256, 0, stream>>>(gate_w,  wgT,  NLAYER, RCH, RCH);
    k_transpose<<<nb(NLAYER*RCH*CCH), 256, 0, stream>>>(cond_w,  wcT,  NLAYER, RCH, CCH);
    k_transpose<<<nb(NLAYER*RCH*CCH), 256, 0, stream>>>(condg_w, wcgT, NLAYER, RCH, CCH);
    k_transpose<<<nb(NLAYER*RCH*RCH), 256, 0, stream>>>(res_w,   wrT,  NLAYER, RCH, RCH);
    k_transpose<<<nb(NLAYER*SCH*RCH), 256, 0, stream>>>(skip_w,  wsT,  NLAYER, SCH, RCH);
    k_transpose<<<nb(RCH*ICH), 256, 0, stream>>>(input_w, inT, 1, RCH, ICH);
    k_transpose<<<nb(SCH*SCH), 256, 0, stream>>>(out1_w,  o1T, 1, SCH, SCH);
    k_transpose<<<nb(OCH*SCH), 256, 0, stream>>>(out2_w,  o2T, 1, OCH, SCH);

    k_input<<<250, 256, 0, stream>>>(x, inT, input_b, h0, skip);

    float* hc = h0;
    float* hn = h1;
    for (int i = 0; i < NLAYER; ++i) {
        int d = 1 << (i % 10);
        k_layerA<<<250, 256, 0, stream>>>(hc, cond,
            wd0T + (size_t)i * RCH * RCH, wd1T + (size_t)i * RCH * RCH,
            wgT  + (size_t)i * RCH * RCH,
            wcT  + (size_t)i * CCH * RCH, wcgT + (size_t)i * CCH * RCH,
            dil_b + i * RCH, cond_b + i * RCH, gate_b + i * RCH, condg_b + i * RCH,
            ob, d);
        k_layerB<<<250, 256, 0, stream>>>(hc, ob,
            wrT + (size_t)i * RCH * RCH, wsT + (size_t)i * RCH * RCH,
            res_b + i * RCH, skip_b + i * RCH, hn, skip);
        float* t = hc; hc = hn; hn = t;
    }
    k_output<<<250, 256, 0, stream>>>(skip, o1T, out1_b, o2T, out2_b, outp);
}

// Round 2
// 4047.203 us; speedup vs baseline: 1.2773x; 1.2773x over previous
//
#include <hip/hip_runtime.h>

#define T_LEN 8000
#define NTPB 125            // time tiles per batch (8000/64)
#define BATCH 2
#define RCH 128
#define SCH 128
#define CCH 80
#define ICH 256
#define OCH 256
#define TILE 64
#define NLAYER 30
#define INV_SQRT2 0.70710678118f

__device__ __forceinline__ void tile_decode(int& b, int& t0) {
    int tile = blockIdx.x;
    b = tile / NTPB;
    t0 = (tile - b * NTPB) * TILE;
}

// ---------------- GEMM helpers: double-buffered weight prefetch ----------------
// pw points at row 0, pre-offset by the wave's channel base. STRIDE = row pitch.
// KD must be even and >= 8.
template<int KD, int OW, int STRIDE>
__device__ __forceinline__ void gemm_pf1(const float* __restrict__ pw,
    const float (* __restrict__ sx)[TILE], int lane, float* __restrict__ acc)
{
    float A[OW], B[OW];
#pragma unroll
    for (int j = 0; j < OW; ++j) A[j] = pw[j];
#pragma unroll
    for (int j = 0; j < OW; ++j) B[j] = pw[STRIDE + j];
    for (int k = 0; k < KD - 4; k += 2) {
        float x0 = sx[k][lane], x1 = sx[k + 1][lane];
#pragma unroll
        for (int j = 0; j < OW; ++j) acc[j] = fmaf(A[j], x0, acc[j]);
#pragma unroll
        for (int j = 0; j < OW; ++j) A[j] = pw[(size_t)(k + 2) * STRIDE + j];
#pragma unroll
        for (int j = 0; j < OW; ++j) acc[j] = fmaf(B[j], x1, acc[j]);
#pragma unroll
        for (int j = 0; j < OW; ++j) B[j] = pw[(size_t)(k + 3) * STRIDE + j];
    }
    float x0 = sx[KD - 4][lane], x1 = sx[KD - 3][lane];
#pragma unroll
    for (int j = 0; j < OW; ++j) acc[j] = fmaf(A[j], x0, acc[j]);
#pragma unroll
    for (int j = 0; j < OW; ++j) A[j] = pw[(size_t)(KD - 2) * STRIDE + j];
#pragma unroll
    for (int j = 0; j < OW; ++j) acc[j] = fmaf(B[j], x1, acc[j]);
#pragma unroll
    for (int j = 0; j < OW; ++j) B[j] = pw[(size_t)(KD - 1) * STRIDE + j];
    x0 = sx[KD - 2][lane]; x1 = sx[KD - 1][lane];
#pragma unroll
    for (int j = 0; j < OW; ++j) acc[j] = fmaf(A[j], x0, acc[j]);
#pragma unroll
    for (int j = 0; j < OW; ++j) acc[j] = fmaf(B[j], x1, acc[j]);
}

// two matrices sharing the same x (e.g. a/g paths)
template<int KD, int STRIDE>
__device__ __forceinline__ void gemm_pf2(const float* __restrict__ pw0,
    const float* __restrict__ pw1,
    const float (* __restrict__ sx)[TILE], int lane,
    float* __restrict__ ac0, float* __restrict__ ac1)
{
    float A0[16], A1[16], B0[16], B1[16];
#pragma unroll
    for (int j = 0; j < 16; ++j) A0[j] = pw0[j];
#pragma unroll
    for (int j = 0; j < 16; ++j) A1[j] = pw1[j];
#pragma unroll
    for (int j = 0; j < 16; ++j) B0[j] = pw0[STRIDE + j];
#pragma unroll
    for (int j = 0; j < 16; ++j) B1[j] = pw1[STRIDE + j];
    for (int k = 0; k < KD - 4; k += 2) {
        float x0 = sx[k][lane], x1 = sx[k + 1][lane];
#pragma unroll
        for (int j = 0; j < 16; ++j) ac0[j] = fmaf(A0[j], x0, ac0[j]);
#pragma unroll
        for (int j = 0; j < 16; ++j) ac1[j] = fmaf(A1[j], x0, ac1[j]);
#pragma unroll
        for (int j = 0; j < 16; ++j) A0[j] = pw0[(size_t)(k + 2) * STRIDE + j];
#pragma unroll
        for (int j = 0; j < 16; ++j) A1[j] = pw1[(size_t)(k + 2) * STRIDE + j];
#pragma unroll
        for (int j = 0; j < 16; ++j) ac0[j] = fmaf(B0[j], x1, ac0[j]);
#pragma unroll
        for (int j = 0; j < 16; ++j) ac1[j] = fmaf(B1[j], x1, ac1[j]);
#pragma unroll
        for (int j = 0; j < 16; ++j) B0[j] = pw0[(size_t)(k + 3) * STRIDE + j];
#pragma unroll
        for (int j = 0; j < 16; ++j) B1[j] = pw1[(size_t)(k + 3) * STRIDE + j];
    }
    float x0 = sx[KD - 4][lane], x1 = sx[KD - 3][lane];
#pragma unroll
    for (int j = 0; j < 16; ++j) ac0[j] = fmaf(A0[j], x0, ac0[j]);
#pragma unroll
    for (int j = 0; j < 16; ++j) ac1[j] = fmaf(A1[j], x0, ac1[j]);
#pragma unroll
    for (int j = 0; j < 16; ++j) A0[j] = pw0[(size_t)(KD - 2) * STRIDE + j];
#pragma unroll
    for (int j = 0; j < 16; ++j) A1[j] = pw1[(size_t)(KD - 2) * STRIDE + j];
#pragma unroll
    for (int j = 0; j < 16; ++j) ac0[j] = fmaf(B0[j], x1, ac0[j]);
#pragma unroll
    for (int j = 0; j < 16; ++j) ac1[j] = fmaf(B1[j], x1, ac1[j]);
#pragma unroll
    for (int j = 0; j < 16; ++j) B0[j] = pw0[(size_t)(KD - 1) * STRIDE + j];
#pragma unroll
    for (int j = 0; j < 16; ++j) B1[j] = pw1[(size_t)(KD - 1) * STRIDE + j];
    x0 = sx[KD - 2][lane]; x1 = sx[KD - 1][lane];
#pragma unroll
    for (int j = 0; j < 16; ++j) ac0[j] = fmaf(A0[j], x0, ac0[j]);
#pragma unroll
    for (int j = 0; j < 16; ++j) ac1[j] = fmaf(A1[j], x0, ac1[j]);
#pragma unroll
    for (int j = 0; j < 16; ++j) ac0[j] = fmaf(B0[j], x1, ac0[j]);
#pragma unroll
    for (int j = 0; j < 16; ++j) ac1[j] = fmaf(B1[j], x1, ac1[j]);
}

__device__ __forceinline__ float gated_act(float av, float gv) {
    float e  = __expf(-2.f * fabsf(av));
    float th = (1.f - e) * __builtin_amdgcn_rcpf(1.f + e);
    th = (av < 0.f) ? -th : th;
    float sg = __builtin_amdgcn_rcpf(1.f + __expf(-gv));
    return th * sg;
}

// ---------------- weight transposes: W[l][o][i] -> wT[l][i][o] ----------------
__global__ void k_transpose(const float* __restrict__ src, float* __restrict__ dst,
                            int L, int O, int I)
{
    int idx = blockIdx.x * blockDim.x + threadIdx.x;
    int tot = L * O * I;
    if (idx >= tot) return;
    int l = idx / (O * I);
    int r = idx - l * O * I;
    int o = r / I;
    int i = r - o * I;
    dst[(l * I + i) * O + o] = src[idx];
}

__global__ void k_transpose_dil(const float* __restrict__ src,
                                float* __restrict__ d0, float* __restrict__ d1)
{
    int idx = blockIdx.x * blockDim.x + threadIdx.x;
    const int tot = NLAYER * RCH * RCH;
    if (idx >= tot) return;
    int l = idx / (RCH * RCH);
    int r = idx - l * RCH * RCH;
    int o = r / RCH;
    int i = r - o * RCH;
    int dsti = (l * RCH + i) * RCH + o;
    d0[dsti] = src[idx * 2 + 0];
    d1[dsti] = src[idx * 2 + 1];
}

// ---------------- input 1x1 conv: h0 = input_w @ x + b; skip = 0 ----------------
__global__ __launch_bounds__(512, 2) void k_input(
    const float* __restrict__ x, const float* __restrict__ inT,
    const float* __restrict__ ib, float* __restrict__ h0, float* __restrict__ skip)
{
    __shared__ float s_x[ICH][TILE];   // 64 KB
    int b, t0; tile_decode(b, t0);
    const int lane = threadIdx.x & 63;
    const int w = threadIdx.x >> 6;
    const float* xb = x + (size_t)b * ICH * T_LEN;
    for (int k = w; k < ICH; k += 8)
        s_x[k][lane] = xb[k * T_LEN + t0 + lane];
    const int cw = __builtin_amdgcn_readfirstlane(w);
    const int c0 = cw * 16;
    float acc[16];
#pragma unroll
    for (int j = 0; j < 16; ++j) acc[j] = ib[c0 + j];
    __syncthreads();
    gemm_pf1<ICH, 16, RCH>(inT + c0, s_x, lane, acc);
    size_t base = (size_t)b * RCH * T_LEN + t0 + lane;
#pragma unroll
    for (int j = 0; j < 16; ++j) {
        h0[base + (size_t)(c0 + j) * T_LEN] = acc[j];
        skip[base + (size_t)(c0 + j) * T_LEN] = 0.f;
    }
}

// ---------------- fused layer: out=tanh(a)sig(g); hnew=(h+Wr@out)*c; skip+=Ws@out ----------------
__global__ __launch_bounds__(512, 2) void k_layer(
    const float* __restrict__ h, const float* __restrict__ cond,
    const float* __restrict__ w0T, const float* __restrict__ w1T,
    const float* __restrict__ wgT, const float* __restrict__ wcT,
    const float* __restrict__ wcgT, const float* __restrict__ wrT,
    const float* __restrict__ wsT,
    const float* __restrict__ db, const float* __restrict__ cb,
    const float* __restrict__ gb, const float* __restrict__ cgb,
    const float* __restrict__ rb, const float* __restrict__ sb,
    float* __restrict__ hnew, float* __restrict__ skip, int dil)
{
    __shared__ float s_h[RCH][TILE];   // h[t] (persistent: seg2 + residual)
    __shared__ float s_b[RCH][TILE];   // h[t-d], later reused for out
    __shared__ float s_c[CCH][TILE];   // condition tile        (total 84 KB)
    int b, t0; tile_decode(b, t0);
    const int lane = threadIdx.x & 63;
    const int w = threadIdx.x >> 6;
    const float* hb  = h    + (size_t)b * RCH * T_LEN;
    const float* cnb = cond + (size_t)b * CCH * T_LEN;
    {
        int ts = t0 - dil + lane;
        for (int k = w; k < RCH; k += 8) {
            s_h[k][lane] = hb[k * T_LEN + t0 + lane];
            s_b[k][lane] = (ts >= 0) ? hb[k * T_LEN + ts] : 0.f;
        }
        for (int k = w; k < CCH; k += 8)
            s_c[k][lane] = cnb[k * T_LEN + t0 + lane];
    }
    const int cw = __builtin_amdgcn_readfirstlane(w);
    const int c0 = cw * 16;
    float a[16], g[16];
#pragma unroll
    for (int j = 0; j < 16; ++j) {
        a[j] = db[c0 + j] + cb[c0 + j];
        g[j] = gb[c0 + j] + cgb[c0 + j];
    }
    __syncthreads();
    gemm_pf1<RCH, 16, RCH>(w0T + c0, s_b, lane, a);                 // a += Wd0 @ h[t-d]
    gemm_pf2<RCH, RCH>(w1T + c0, wgT + c0, s_h, lane, a, g);        // a += Wd1@h; g += Wg@h
    gemm_pf2<CCH, RCH>(wcT + c0, wcgT + c0, s_c, lane, a, g);       // a += Wc@c; g += Wcg@c
    float ov[16];
#pragma unroll
    for (int j = 0; j < 16; ++j) ov[j] = gated_act(a[j], g[j]);
    __syncthreads();                      // all waves done reading s_b (seg1)
#pragma unroll
    for (int j = 0; j < 16; ++j) s_b[c0 + j][lane] = ov[j];
    __syncthreads();
    float r[16], s[16];
#pragma unroll
    for (int j = 0; j < 16; ++j) { r[j] = rb[c0 + j]; s[j] = sb[c0 + j]; }
    gemm_pf2<RCH, RCH>(wrT + c0, wsT + c0, s_b, lane, r, s);        // r += Wr@out; s += Ws@out
    const size_t base = (size_t)b * RCH * T_LEN + t0 + lane;
#pragma unroll
    for (int j = 0; j < 16; ++j) {
        size_t idx = base + (size_t)(c0 + j) * T_LEN;
        hnew[idx] = (s_h[c0 + j][lane] + r[j]) * INV_SQRT2;
        skip[idx] += s[j];
    }
}

// ---------------- output head ----------------
__global__ __launch_bounds__(512, 2) void k_output(
    const float* __restrict__ skip, const float* __restrict__ w1T,
    const float* __restrict__ b1, const float* __restrict__ w2T,
    const float* __restrict__ b2, float* __restrict__ out)
{
    __shared__ float s_a[SCH][TILE];
    __shared__ float s_y[SCH][TILE];
    int b, t0; tile_decode(b, t0);
    const int lane = threadIdx.x & 63;
    const int w = threadIdx.x >> 6;
    const float* sk = skip + (size_t)b * SCH * T_LEN;
    for (int k = w; k < SCH; k += 8)
        s_a[k][lane] = sk[k * T_LEN + t0 + lane];
    const int cw = __builtin_amdgcn_readfirstlane(w);
    const int c0 = cw * 16;
    float y[16];
#pragma unroll
    for (int j = 0; j < 16; ++j) y[j] = b1[c0 + j];
    __syncthreads();
    gemm_pf1<SCH, 16, SCH>(w1T + c0, s_a, lane, y);
#pragma unroll
    for (int j = 0; j < 16; ++j) s_y[c0 + j][lane] = fmaxf(y[j], 0.f);
    __syncthreads();
    const int c1 = cw * 32;
    float o[32];
#pragma unroll
    for (int j = 0; j < 32; ++j) o[j] = b2[c1 + j];
    gemm_pf1<SCH, 32, OCH>(w2T + c1, s_y, lane, o);
    float* outp = out + (size_t)b * OCH * T_LEN + t0 + lane;
#pragma unroll
    for (int j = 0; j < 32; ++j) outp[(size_t)(c1 + j) * T_LEN] = o[j];
}

extern "C" void kernel_launch(void* const* d_in, const int* in_sizes, int n_in,
                              void* d_out, int out_size, void* d_ws, size_t ws_size,
                              hipStream_t stream)
{
    const float* x        = (const float*)d_in[0];
    const float* cond     = (const float*)d_in[1];
    const float* input_w  = (const float*)d_in[2];
    const float* input_b  = (const float*)d_in[3];
    const float* dil_w    = (const float*)d_in[4];
    const float* dil_b    = (const float*)d_in[5];
    const float* gate_w   = (const float*)d_in[6];
    const float* gate_b   = (const float*)d_in[7];
    const float* cond_w   = (const float*)d_in[8];
    const float* cond_b   = (const float*)d_in[9];
    const float* condg_w  = (const float*)d_in[10];
    const float* condg_b  = (const float*)d_in[11];
    const float* res_w    = (const float*)d_in[12];
    const float* res_b    = (const float*)d_in[13];
    const float* skip_w   = (const float*)d_in[14];
    const float* skip_b   = (const float*)d_in[15];
    const float* out1_w   = (const float*)d_in[16];
    const float* out1_b   = (const float*)d_in[17];
    const float* out2_w   = (const float*)d_in[18];
    const float* out2_b   = (const float*)d_in[19];
    float* outp = (float*)d_out;
    float* ws = (float*)d_ws;

    const size_t ACT = (size_t)BATCH * RCH * T_LEN;   // 2,048,000 floats
    float* h0   = ws;
    float* h1   = h0   + ACT;
    float* ob   = h1   + ACT;   // unused (kept for layout stability)
    float* skip = ob   + ACT;
    float* wd0T = skip + ACT;
    float* wd1T = wd0T + (size_t)NLAYER * RCH * RCH;
    float* wgT  = wd1T + (size_t)NLAYER * RCH * RCH;
    float* wcT  = wgT  + (size_t)NLAYER * RCH * RCH;
    float* wcgT = wcT  + (size_t)NLAYER * CCH * RCH;
    float* wrT  = wcgT + (size_t)NLAYER * CCH * RCH;
    float* wsT  = wrT  + (size_t)NLAYER * RCH * RCH;
    float* inT  = wsT  + (size_t)NLAYER * RCH * RCH;
    float* o1T  = inT  + (size_t)ICH * RCH;
    float* o2T  = o1T  + (size_t)SCH * SCH;

    auto nb = [](int n) { return dim3((n + 255) / 256); };
    k_transpose_dil<<<nb(NLAYER*RCH*RCH), 256, 0, stream>>>(dil_w, wd0T, wd1T);
    k_transpose<<<nb(NLAYER*RCH*RCH), 256, 0, stream>>>(gate_w,  wgT,  NLAYER, RCH, RCH);
    k_transpose<<<nb(NLAYER*RCH*CCH), 256, 0, stream>>>(cond_w,  wcT,  NLAYER, RCH, CCH);
    k_transpose<<<nb(NLAYER*RCH*CCH), 256, 0, stream>>>(condg_w, wcgT, NLAYER, RCH, CCH);
    k_transpose<<<nb(NLAYER*RCH*RCH), 256, 0, stream>>>(res_w,   wrT,  NLAYER, RCH, RCH);
    k_transpose<<<nb(NLAYER*SCH*RCH), 256, 0, stream>>>(skip_w,  wsT,  NLAYER, SCH, RCH);
    k_transpose<<<nb(RCH*ICH), 256, 0, stream>>>(input_w, inT, 1, RCH, ICH);
    k_transpose<<<nb(SCH*SCH), 256, 0, stream>>>(out1_w,  o1T, 1, SCH, SCH);
    k_transpose<<<nb(OCH*SCH), 256, 0, stream>>>(out2_w,  o2T, 1, OCH, SCH);

    k_input<<<250, 512, 0, stream>>>(x, inT, input_b, h0, skip);

    float* hc = h0;
    float* hn = h1;
    for (int i = 0; i < NLAYER; ++i) {
        int d = 1 << (i % 10);
        k_layer<<<250, 512, 0, stream>>>(hc, cond,
            wd0T + (size_t)i * RCH * RCH, wd1T + (size_t)i * RCH * RCH,
            wgT  + (size_t)i * RCH * RCH,
            wcT  + (size_t)i * CCH * RCH, wcgT + (size_t)i * CCH * RCH,
            wrT  + (size_t)i * RCH * RCH, wsT  + (size_t)i * RCH * RCH,
            dil_b + i * RCH, cond_b + i * RCH, gate_b + i * RCH, condg_b + i * RCH,
            res_b + i * RCH, skip_b + i * RCH,
            hn, skip, d);
        float* t = hc; hc = hn; hn = t;
    }
    k_output<<<250, 512, 0, stream>>>(skip, o1T, out1_b, o2T, out2_b, outp);
}

// Round 3
// 1667.720 us; speedup vs baseline: 3.0998x; 2.4268x over previous
//
#include <hip/hip_runtime.h>
#include <hip/hip_cooperative_groups.h>

namespace cg = cooperative_groups;

#define T_LEN 8000
#define NTPB 125
#define NBLK 250
#define NLAYER 30
#define INV_SQRT2 0.70710678118f

typedef short bf16x8 __attribute__((ext_vector_type(8)));
typedef short s16x4  __attribute__((ext_vector_type(4)));
typedef float f32x4  __attribute__((ext_vector_type(4)));

// LDS regions in SHORTS (each 8192 shorts = 16 KB)
#define R_HT   0        // h[t] bf16 tile, pitch 128
#define R_HD   8192     // h[t-d] tile / s_skip in head, pitch 128
#define R_OUT  16384    // gated out tile / s_y in head, pitch 128
#define R_CND  24576    // cond tile (k=80 -> 1.0 bias col), pitch 128
#define R_X    8192     // input conv x tile, pitch 256 (overlays HD+OUT)

// wpack frag offsets (shorts): frag = 512 shorts (64 lanes x 8 bf16)
#define LAYER_STRIDE 106496   // 26 ksteps * 8 frags * 512
#define IN_OFF   3194880      // 6240*512
#define OUT1_OFF 3227648      // 6304*512
#define OUT2_OFF 3244032      // 6336*512

__device__ __forceinline__ unsigned short f2bf_u(float f) {
    union { float f; unsigned u; } v; v.f = f;
    unsigned u = v.u + 0x7FFFu + ((v.u >> 16) & 1u);   // RNE
    return (unsigned short)(u >> 16);
}
__device__ __forceinline__ short f2bf(float f) { return (short)f2bf_u(f); }
__device__ __forceinline__ unsigned pack2(float a, float b) {
    return (unsigned)f2bf_u(a) | ((unsigned)f2bf_u(b) << 16);
}

__device__ __forceinline__ float gated_act(float av, float gv) {
    float e  = __expf(-2.f * fabsf(av));
    float th = (1.f - e) * __builtin_amdgcn_rcpf(1.f + e);
    th = (av < 0.f) ? -th : th;
    float sg = __builtin_amdgcn_rcpf(1.f + __expf(-gv));
    return th * sg;
}

// C[ch][t] += W @ X : A-frags from global wpack, B-frags from swizzled LDS tile
template<int NK, int MT, int KSP>
__device__ __forceinline__ void gemm(const short* __restrict__ wbase, const short* sm,
                                     int xrow, int sw, int lg, f32x4* acc)
{
#pragma unroll
    for (int ks = 0; ks < NK; ++ks) {
        bf16x8 B = *(const bf16x8*)&sm[xrow + ((ks*32 + lg*8) ^ sw)];
#pragma unroll
        for (int mt = 0; mt < MT; ++mt) {
            bf16x8 A = *(const bf16x8*)&wbase[(size_t)(ks*KSP + mt) * 512];
            acc[mt] = __builtin_amdgcn_mfma_f32_16x16x32_bf16(A, B, acc[mt], 0, 0, 0);
        }
    }
}

// ---------------- weight pack: all matrices -> A-fragment layout bf16 ----------------
__global__ __launch_bounds__(256) void k_pack(
    const float* __restrict__ dil_w, const float* __restrict__ gate_w,
    const float* __restrict__ cond_w, const float* __restrict__ condg_w,
    const float* __restrict__ res_w, const float* __restrict__ skip_w,
    const float* __restrict__ input_w, const float* __restrict__ out1_w,
    const float* __restrict__ out2_w,
    const float* __restrict__ dil_b, const float* __restrict__ cond_b,
    const float* __restrict__ gate_b, const float* __restrict__ condg_b,
    short* __restrict__ wp)
{
    int gid = blockIdx.x * 256 + threadIdx.x;
    if (gid >= 6400 * 64) return;
    int fid = gid >> 6, lane = gid & 63;
    int lr = lane & 15, lg = lane >> 4;
    float v[8];
    if (fid < 6240) {
        int layer = fid / 208;
        int r = fid - layer * 208;
        int kl = r >> 3, mt = r & 7;
        int m = mt * 16 + lr;
        int mi = layer * 128 + m;
        int seg, ks;
        if      (kl < 4)  { seg = 0; ks = kl;      }
        else if (kl < 8)  { seg = 1; ks = kl - 4;  }
        else if (kl < 11) { seg = 2; ks = kl - 8;  }
        else if (kl < 15) { seg = 3; ks = kl - 11; }
        else if (kl < 18) { seg = 4; ks = kl - 15; }
        else if (kl < 22) { seg = 5; ks = kl - 18; }
        else              { seg = 6; ks = kl - 22; }
        int kb = ks * 32 + lg * 8;
#pragma unroll
        for (int e = 0; e < 8; ++e) {
            int k = kb + e;
            float val;
            switch (seg) {
                case 0:  val = dil_w[((size_t)mi * 128 + k) * 2];     break;
                case 1:  val = dil_w[((size_t)mi * 128 + k) * 2 + 1]; break;
                case 2:  val = (k < 80) ? cond_w[(size_t)mi * 80 + k]
                               : ((k == 80) ? dil_b[mi] + cond_b[mi] : 0.f); break;
                case 3:  val = gate_w[(size_t)mi * 128 + k]; break;
                case 4:  val = (k < 80) ? condg_w[(size_t)mi * 80 + k]
                               : ((k == 80) ? gate_b[mi] + condg_b[mi] : 0.f); break;
                case 5:  val = res_w[(size_t)mi * 128 + k]; break;
                default: val = skip_w[(size_t)mi * 128 + k]; break;
            }
            v[e] = val;
        }
    } else if (fid < 6304) {           // input conv, K=256: 8 ksteps x 8 mt
        int f = fid - 6240; int ks = f >> 3, mt = f & 7;
        int m = mt * 16 + lr; int kb = ks * 32 + lg * 8;
#pragma unroll
        for (int e = 0; e < 8; ++e) v[e] = input_w[(size_t)m * 256 + kb + e];
    } else if (fid < 6336) {           // out1, 128x128
        int f = fid - 6304; int ks = f >> 3, mt = f & 7;
        int m = mt * 16 + lr; int kb = ks * 32 + lg * 8;
#pragma unroll
        for (int e = 0; e < 8; ++e) v[e] = out1_w[(size_t)m * 128 + kb + e];
    } else {                           // out2, 256x128: [ks][16 mt]
        int f = fid - 6336; int ks = f >> 4, mt = f & 15;
        int m = mt * 16 + lr; int kb = ks * 32 + lg * 8;
#pragma unroll
        for (int e = 0; e < 8; ++e) v[e] = out2_w[(size_t)m * 128 + kb + e];
    }
    short* dst = wp + (size_t)fid * 512 + lane * 8;
#pragma unroll
    for (int e = 0; e < 8; ++e) dst[e] = f2bf(v[e]);
}

// ---------------- persistent fused WaveNet ----------------
__global__ __launch_bounds__(512, 2) void k_wavenet(
    const float* __restrict__ x, const float* __restrict__ cond,
    const short* __restrict__ wp,
    float* __restrict__ hb0, float* __restrict__ hb1,
    const float* __restrict__ ib, const float* __restrict__ rbias,
    const float* __restrict__ sbias, const float* __restrict__ b1,
    const float* __restrict__ b2, float* __restrict__ outp)
{
    __shared__ short sm[32768];   // 64 KB
    cg::grid_group grid = cg::this_grid();

    const int tid  = threadIdx.x;
    const int lane = tid & 63;
    const int w    = tid >> 6;
    const int wv   = __builtin_amdgcn_readfirstlane(w);
    const int wm   = wv >> 2, wn = wv & 3;
    const int lr   = lane & 15, lg = lane >> 4;
    const int bidx = blockIdx.x;
    const int b    = bidx / NTPB;
    const int t0   = (bidx - b * NTPB) * 64;
    const int tl   = wn * 16 + lr;          // local t of this lane's D column
    const int swz  = (tl & 7) << 3;         // read-side swizzle (shorts)
    const int tg   = t0 + tl;               // global t
    const int woff = (wm * 4) * 512 + lane * 8;

    // ---- stage x tile (bf16, pitch 256) and cond tile (pitch 128, k=80 -> 1.0) ----
    {
        const int ls = (lane & 7) << 3;
        const float* xb = x + (size_t)b * 256 * T_LEN + t0 + lane;
#pragma unroll
        for (int it = 0; it < 16; ++it) {
            int chp = w + it * 8;           // 0..127
            unsigned pk = pack2(xb[(size_t)(2 * chp) * T_LEN], xb[(size_t)(2 * chp + 1) * T_LEN]);
            *(unsigned*)&sm[R_X + lane * 256 + ((2 * chp) ^ ls)] = pk;
        }
        const float* cb_ = cond + (size_t)b * 80 * T_LEN + t0 + lane;
#pragma unroll
        for (int it = 0; it < 6; ++it) {
            int kp = w + it * 8;            // 0..47
            int k0 = 2 * kp, k1 = k0 + 1;
            float v0 = (k0 < 80) ? cb_[(size_t)k0 * T_LEN] : ((k0 == 80) ? 1.f : 0.f);
            float v1 = (k1 < 80) ? cb_[(size_t)k1 * T_LEN] : 0.f;
            *(unsigned*)&sm[R_CND + lane * 128 + (k0 ^ ls)] = pack2(v0, v1);
        }
    }
    __syncthreads();

    // ---- input 1x1 conv: h0 = Win @ x + ib ----
    f32x4 hres[4];
    {
        f32x4 acc[4];
#pragma unroll
        for (int mt = 0; mt < 4; ++mt) acc[mt] = (f32x4){0.f, 0.f, 0.f, 0.f};
        gemm<8, 4, 8>(wp + IN_OFF + woff, sm, R_X + tl * 256, swz, lg, acc);
#pragma unroll
        for (int mt = 0; mt < 4; ++mt) {
            int chb = wm * 64 + mt * 16 + lg * 4;
            f32x4 bv = {ib[chb], ib[chb + 1], ib[chb + 2], ib[chb + 3]};
            hres[mt] = acc[mt] + bv;
        }
    }
    // write s_ht (bf16) + hb0 (fp32)
#pragma unroll
    for (int mt = 0; mt < 4; ++mt) {
        int k0 = wm * 64 + mt * 16 + lg * 4;
        s16x4 pk = {f2bf(hres[mt][0]), f2bf(hres[mt][1]), f2bf(hres[mt][2]), f2bf(hres[mt][3])};
        *(s16x4*)&sm[R_HT + tl * 128 + (k0 ^ swz)] = pk;
        float* hp = hb0 + ((size_t)(b * 128 + k0)) * T_LEN + tg;
        hp[0] = hres[mt][0]; hp[T_LEN] = hres[mt][1];
        hp[2 * T_LEN] = hres[mt][2]; hp[3 * T_LEN] = hres[mt][3];
    }

    f32x4 skp[4];
#pragma unroll
    for (int mt = 0; mt < 4; ++mt) skp[mt] = (f32x4){0.f, 0.f, 0.f, 0.f};

    // ---- 30 layers ----
    for (int li = 0; li < NLAYER; ++li) {
        grid.sync();                        // all hnew visible (cross-XCD)
        const float* hc = (li & 1) ? hb1 : hb0;
        float* hn       = (li & 1) ? hb0 : hb1;
        const int d = 1 << (li % 10);
        {   // stage h[t-d] tile
            const int ts = t0 - d + lane;
            const int ls = (lane & 7) << 3;
            const float* hsrc = hc + (size_t)b * 128 * T_LEN + ts;
#pragma unroll
            for (int it = 0; it < 8; ++it) {
                int chp = w + it * 8;       // 0..63
                float v0 = 0.f, v1 = 0.f;
                if (ts >= 0) {
                    v0 = hsrc[(size_t)(2 * chp) * T_LEN];
                    v1 = hsrc[(size_t)(2 * chp + 1) * T_LEN];
                }
                *(unsigned*)&sm[R_HD + lane * 128 + ((2 * chp) ^ ls)] = pack2(v0, v1);
            }
        }
        __syncthreads();
        const short* wl = wp + (size_t)li * LAYER_STRIDE;
        f32x4 aa[4], ag[4];
#pragma unroll
        for (int mt = 0; mt < 4; ++mt) { aa[mt] = (f32x4){0.f,0.f,0.f,0.f}; ag[mt] = (f32x4){0.f,0.f,0.f,0.f}; }
        gemm<4, 4, 8>(wl + 0  * 4096 + woff, sm, R_HD  + tl * 128, swz, lg, aa); // Wd0 @ h[t-d]
        gemm<4, 4, 8>(wl + 4  * 4096 + woff, sm, R_HT  + tl * 128, swz, lg, aa); // Wd1 @ h[t]
        gemm<3, 4, 8>(wl + 8  * 4096 + woff, sm, R_CND + tl * 128, swz, lg, aa); // Wc @ cond (+bias col)
        gemm<4, 4, 8>(wl + 11 * 4096 + woff, sm, R_HT  + tl * 128, swz, lg, ag); // Wg @ h[t]
        gemm<3, 4, 8>(wl + 15 * 4096 + woff, sm, R_CND + tl * 128, swz, lg, ag); // Wcg @ cond (+bias col)
        // out = tanh(a)*sigmoid(g) -> s_out bf16
#pragma unroll
        for (int mt = 0; mt < 4; ++mt) {
            int k0 = wm * 64 + mt * 16 + lg * 4;
            s16x4 pk;
#pragma unroll
            for (int j = 0; j < 4; ++j) pk[j] = f2bf(gated_act(aa[mt][j], ag[mt][j]));
            *(s16x4*)&sm[R_OUT + tl * 128 + (k0 ^ swz)] = pk;
        }
        __syncthreads();
        const float* rbl = rbias + li * 128;
        const float* sbl = sbias + li * 128;
        f32x4 rbv[4], sbv[4];
#pragma unroll
        for (int mt = 0; mt < 4; ++mt) {
            int chb = wm * 64 + mt * 16 + lg * 4;
            rbv[mt] = (f32x4){rbl[chb], rbl[chb+1], rbl[chb+2], rbl[chb+3]};
            sbv[mt] = (f32x4){sbl[chb], sbl[chb+1], sbl[chb+2], sbl[chb+3]};
        }
        f32x4 ar[4], as2[4];
#pragma unroll
        for (int mt = 0; mt < 4; ++mt) { ar[mt] = (f32x4){0.f,0.f,0.f,0.f}; as2[mt] = (f32x4){0.f,0.f,0.f,0.f}; }
        gemm<4, 4, 8>(wl + 18 * 4096 + woff, sm, R_OUT + tl * 128, swz, lg, ar);  // Wr @ out
        gemm<4, 4, 8>(wl + 22 * 4096 + woff, sm, R_OUT + tl * 128, swz, lg, as2); // Ws @ out
        const bool last = (li == NLAYER - 1);
#pragma unroll
        for (int mt = 0; mt < 4; ++mt) {
            hres[mt] = (hres[mt] + ar[mt] + rbv[mt]) * INV_SQRT2;
            skp[mt]  = skp[mt] + as2[mt] + sbv[mt];
        }
        if (!last) {
#pragma unroll
            for (int mt = 0; mt < 4; ++mt) {
                int k0 = wm * 64 + mt * 16 + lg * 4;
                s16x4 pk = {f2bf(hres[mt][0]), f2bf(hres[mt][1]), f2bf(hres[mt][2]), f2bf(hres[mt][3])};
                *(s16x4*)&sm[R_HT + tl * 128 + (k0 ^ swz)] = pk;
                float* hp = hn + ((size_t)(b * 128 + k0)) * T_LEN + tg;
                hp[0] = hres[mt][0]; hp[T_LEN] = hres[mt][1];
                hp[2 * T_LEN] = hres[mt][2]; hp[3 * T_LEN] = hres[mt][3];
            }
        }
    }

    // ---- output head ----
    __syncthreads();
#pragma unroll
    for (int mt = 0; mt < 4; ++mt) {        // skip -> s_skip (R_HD) bf16
        int k0 = wm * 64 + mt * 16 + lg * 4;
        s16x4 pk = {f2bf(skp[mt][0]), f2bf(skp[mt][1]), f2bf(skp[mt][2]), f2bf(skp[mt][3])};
        *(s16x4*)&sm[R_HD + tl * 128 + (k0 ^ swz)] = pk;
    }
    __syncthreads();
    f32x4 ay[4];
#pragma unroll
    for (int mt = 0; mt < 4; ++mt) ay[mt] = (f32x4){0.f,0.f,0.f,0.f};
    gemm<4, 4, 8>(wp + OUT1_OFF + woff, sm, R_HD + tl * 128, swz, lg, ay);
#pragma unroll
    for (int mt = 0; mt < 4; ++mt) {        // y = relu(. + b1) -> s_y (R_OUT) bf16
        int chb = wm * 64 + mt * 16 + lg * 4;
        s16x4 pk;
#pragma unroll
        for (int j = 0; j < 4; ++j) pk[j] = f2bf(fmaxf(ay[mt][j] + b1[chb + j], 0.f));
        *(s16x4*)&sm[R_OUT + tl * 128 + (chb ^ swz)] = pk;
    }
    __syncthreads();
    f32x4 ao[8];
#pragma unroll
    for (int mt = 0; mt < 8; ++mt) ao[mt] = (f32x4){0.f,0.f,0.f,0.f};
    gemm<4, 8, 16>(wp + OUT2_OFF + (wm * 8) * 512 + lane * 8, sm, R_OUT + tl * 128, swz, lg, ao);
#pragma unroll
    for (int mt = 0; mt < 8; ++mt) {
        int ch2 = wm * 128 + mt * 16 + lg * 4;
        float* op = outp + ((size_t)(b * 256 + ch2)) * T_LEN + tg;
        op[0]         = ao[mt][0] + b2[ch2];
        op[T_LEN]     = ao[mt][1] + b2[ch2 + 1];
        op[2 * T_LEN] = ao[mt][2] + b2[ch2 + 2];
        op[3 * T_LEN] = ao[mt][3] + b2[ch2 + 3];
    }
}

extern "C" void kernel_launch(void* const* d_in, const int* in_sizes, int n_in,
                              void* d_out, int out_size, void* d_ws, size_t ws_size,
                              hipStream_t stream)
{
    const float* x       = (const float*)d_in[0];
    const float* cond    = (const float*)d_in[1];
    const float* input_w = (const float*)d_in[2];
    const float* input_b = (const float*)d_in[3];
    const float* dil_w   = (const float*)d_in[4];
    const float* dil_b   = (const float*)d_in[5];
    const float* gate_w  = (const float*)d_in[6];
    const float* gate_b  = (const float*)d_in[7];
    const float* cond_w  = (const float*)d_in[8];
    const float* cond_b  = (const float*)d_in[9];
    const float* condg_w = (const float*)d_in[10];
    const float* condg_b = (const float*)d_in[11];
    const float* res_w   = (const float*)d_in[12];
    const float* res_b   = (const float*)d_in[13];
    const float* skip_w  = (const float*)d_in[14];
    const float* skip_b  = (const float*)d_in[15];
    const float* out1_w  = (const float*)d_in[16];
    const float* out1_b  = (const float*)d_in[17];
    const float* out2_w  = (const float*)d_in[18];
    const float* out2_b  = (const float*)d_in[19];
    float* outp = (float*)d_out;
    float* ws   = (float*)d_ws;

    const size_t ACT = (size_t)2 * 128 * T_LEN;   // 2,048,000 floats
    float* hb0 = ws;
    float* hb1 = hb0 + ACT;
    short* wpk = (short*)(hb1 + ACT);             // 3,276,800 shorts = 6.55 MB

    k_pack<<<1600, 256, 0, stream>>>(dil_w, gate_w, cond_w, condg_w, res_w, skip_w,
                                     input_w, out1_w, out2_w,
                                     dil_b, cond_b, gate_b, condg_b, wpk);

    void* args[] = {(void*)&x, (void*)&cond, (void*)&wpk, (void*)&hb0, (void*)&hb1,
                    (void*)&input_b, (void*)&res_b, (void*)&skip_b,
                    (void*)&out1_b, (void*)&out2_b, (void*)&outp};
    hipLaunchCooperativeKernel((void*)k_wavenet, dim3(NBLK), dim3(512), args, 0, stream);
}

// Round 4
// 400.580 us; speedup vs baseline: 12.9054x; 4.1633x over previous
//
#include <hip/hip_runtime.h>

#define T_LEN 8000
#define NTPB 125
#define NBLK 250
#define NTILES 250
#define NLAYER 30
#define INV_SQRT2 0.70710678118f

typedef short bf16x8 __attribute__((ext_vector_type(8)));
typedef short s16x4  __attribute__((ext_vector_type(4)));
typedef float f32x4  __attribute__((ext_vector_type(4)));

// LDS layout (shorts): [kb][t][8] k-block-major tiles, 8192 shorts each
#define R_HT   0        // own h[t] bf16 (16 kb)
#define R_HD   8192     // h[t-d] / skip in head
#define R_OUT  16384    // gated out / y in head
#define R_CND  24576    // cond, 12 kb (k=80 -> 1.0 bias col, rest 0)
#define R_X    8192     // input x tile, 32 kb (overlays HD+OUT)

#define LAYER_STRIDE 106496   // 26 ksteps * 8 frags * 512 shorts
#define IN_OFF   3194880
#define OUT1_OFF 3227648
#define OUT2_OFF 3244032

__device__ __forceinline__ unsigned short f2bf_u(float f) {
    union { float f; unsigned u; } v; v.f = f;
    unsigned u = v.u + 0x7FFFu + ((v.u >> 16) & 1u);   // RNE
    return (unsigned short)(u >> 16);
}
__device__ __forceinline__ short f2bf(float f) { return (short)f2bf_u(f); }

__device__ __forceinline__ float gated_act(float av, float gv) {
    float e  = __expf(-2.f * fabsf(av));
    float th = (1.f - e) * __builtin_amdgcn_rcpf(1.f + e);
    th = (av < 0.f) ? -th : th;
    float sg = __builtin_amdgcn_rcpf(1.f + __expf(-gv));
    return th * sg;
}

// LLC-coherent (agent-scope) accessors: cross-XCD safe without cache flushes
__device__ __forceinline__ float ld_cg(const float* p) {
    return __hip_atomic_load(p, __ATOMIC_RELAXED, __HIP_MEMORY_SCOPE_AGENT);
}
__device__ __forceinline__ void st_cg(float* p, float v) {
    __hip_atomic_store(p, v, __ATOMIC_RELAXED, __HIP_MEMORY_SCOPE_AGENT);
}
__device__ __forceinline__ int ld_flag(const int* p) {
    return __hip_atomic_load(p, __ATOMIC_RELAXED, __HIP_MEMORY_SCOPE_AGENT);
}
__device__ __forceinline__ void st_flag(int* p, int v) {
    __hip_atomic_store(p, v, __ATOMIC_RELAXED, __HIP_MEMORY_SCOPE_AGENT);
}
__device__ __forceinline__ void wait_flag(const int* p) {
    while (ld_flag(p) == 0) __builtin_amdgcn_s_sleep(2);
}

// C[ch][t] += W @ X : A-frags from global wpack, B-frags from [kb][t][8] LDS
template<int NK, int MT, int KSP>
__device__ __forceinline__ void gemm(const short* __restrict__ wbase, const short* sm,
                                     int xbase, int lg, f32x4* acc)
{
#pragma unroll
    for (int ks = 0; ks < NK; ++ks) {
        bf16x8 B = *(const bf16x8*)&sm[xbase + (ks * 4 + lg) * 512];
#pragma unroll
        for (int mt = 0; mt < MT; ++mt) {
            bf16x8 A = *(const bf16x8*)&wbase[(size_t)(ks * KSP + mt) * 512];
            acc[mt] = __builtin_amdgcn_mfma_f32_16x16x32_bf16(A, B, acc[mt], 0, 0, 0);
        }
    }
}

// ---------------- weight pack + flag zeroing ----------------
__global__ __launch_bounds__(256) void k_pack(
    const float* __restrict__ dil_w, const float* __restrict__ gate_w,
    const float* __restrict__ cond_w, const float* __restrict__ condg_w,
    const float* __restrict__ res_w, const float* __restrict__ skip_w,
    const float* __restrict__ input_w, const float* __restrict__ out1_w,
    const float* __restrict__ out2_w,
    const float* __restrict__ dil_b, const float* __restrict__ cond_b,
    const float* __restrict__ gate_b, const float* __restrict__ condg_b,
    short* __restrict__ wp, int* __restrict__ rdy, int* __restrict__ dn)
{
    int gid = blockIdx.x * 256 + threadIdx.x;
    if (gid < NLAYER * NTILES) { rdy[gid] = 0; dn[gid] = 0; }
    if (gid >= 6400 * 64) return;
    int fid = gid >> 6, lane = gid & 63;
    int lr = lane & 15, lg = lane >> 4;
    float v[8];
    if (fid < 6240) {
        int layer = fid / 208;
        int r = fid - layer * 208;
        int kl = r >> 3, mt = r & 7;
        int m = mt * 16 + lr;
        int mi = layer * 128 + m;
        int seg, ks;
        if      (kl < 4)  { seg = 0; ks = kl;      }
        else if (kl < 8)  { seg = 1; ks = kl - 4;  }
        else if (kl < 11) { seg = 2; ks = kl - 8;  }
        else if (kl < 15) { seg = 3; ks = kl - 11; }
        else if (kl < 18) { seg = 4; ks = kl - 15; }
        else if (kl < 22) { seg = 5; ks = kl - 18; }
        else              { seg = 6; ks = kl - 22; }
        int kb = ks * 32 + lg * 8;
#pragma unroll
        for (int e = 0; e < 8; ++e) {
            int k = kb + e;
            float val;
            switch (seg) {
                case 0:  val = dil_w[((size_t)mi * 128 + k) * 2];     break;
                case 1:  val = dil_w[((size_t)mi * 128 + k) * 2 + 1]; break;
                case 2:  val = (k < 80) ? cond_w[(size_t)mi * 80 + k]
                               : ((k == 80) ? dil_b[mi] + cond_b[mi] : 0.f); break;
                case 3:  val = gate_w[(size_t)mi * 128 + k]; break;
                case 4:  val = (k < 80) ? condg_w[(size_t)mi * 80 + k]
                               : ((k == 80) ? gate_b[mi] + condg_b[mi] : 0.f); break;
                case 5:  val = res_w[(size_t)mi * 128 + k]; break;
                default: val = skip_w[(size_t)mi * 128 + k]; break;
            }
            v[e] = val;
        }
    } else if (fid < 6304) {
        int f = fid - 6240; int ks = f >> 3, mt = f & 7;
        int m = mt * 16 + lr; int kb = ks * 32 + lg * 8;
#pragma unroll
        for (int e = 0; e < 8; ++e) v[e] = input_w[(size_t)m * 256 + kb + e];
    } else if (fid < 6336) {
        int f = fid - 6304; int ks = f >> 3, mt = f & 7;
        int m = mt * 16 + lr; int kb = ks * 32 + lg * 8;
#pragma unroll
        for (int e = 0; e < 8; ++e) v[e] = out1_w[(size_t)m * 128 + kb + e];
    } else {
        int f = fid - 6336; int ks = f >> 4, mt = f & 15;
        int m = mt * 16 + lr; int kb = ks * 32 + lg * 8;
#pragma unroll
        for (int e = 0; e < 8; ++e) v[e] = out2_w[(size_t)m * 128 + kb + e];
    }
    short* dst = wp + (size_t)fid * 512 + lane * 8;
#pragma unroll
    for (int e = 0; e < 8; ++e) dst[e] = f2bf(v[e]);
}

// ---------------- persistent fused WaveNet (p2p flag sync) ----------------
__global__ __launch_bounds__(512, 2) void k_wavenet(
    const float* __restrict__ x, const float* __restrict__ cond,
    const short* __restrict__ wp,
    float* __restrict__ hb0, float* __restrict__ hb1,
    const float* __restrict__ ib, const float* __restrict__ rbias,
    const float* __restrict__ sbias, const float* __restrict__ b1,
    const float* __restrict__ b2, float* __restrict__ outp,
    int* __restrict__ rdy, int* __restrict__ dn)
{
    __shared__ short sm[30720];   // 60 KB

    const int tid  = threadIdx.x;
    const int lane = tid & 63;
    const int w    = tid >> 6;
    const int wv   = __builtin_amdgcn_readfirstlane(w);
    const int wm   = wv >> 2, wn = wv & 3;
    const int lr   = lane & 15, lg = lane >> 4;
    const int bidx = blockIdx.x;
    const int b    = bidx / NTPB;
    const int ti   = bidx - b * NTPB;
    const int t0   = ti * 64;
    const int tl   = wn * 16 + lr;
    const int tg   = t0 + tl;
    const int woff = (wm * 4) * 512 + lane * 8;

    // ---- stage x tile (32 kb) and cond tile (12 kb) ----
    {
        const float* xb = x + (size_t)b * 256 * T_LEN + t0 + lane;
#pragma unroll
        for (int it = 0; it < 4; ++it) {
            int kb = w * 4 + it;              // 0..31
            bf16x8 pk;
#pragma unroll
            for (int e = 0; e < 8; ++e) pk[e] = f2bf(xb[(size_t)(kb * 8 + e) * T_LEN]);
            *(bf16x8*)&sm[R_X + (kb * 64 + lane) * 8] = pk;
        }
        const float* cb_ = cond + (size_t)b * 80 * T_LEN + t0 + lane;
        for (int kb = w; kb < 12; kb += 8) {
            bf16x8 pk;
#pragma unroll
            for (int e = 0; e < 8; ++e) {
                int ch = kb * 8 + e;
                float v = (ch < 80) ? cb_[(size_t)ch * T_LEN] : ((ch == 80) ? 1.f : 0.f);
                pk[e] = f2bf(v);
            }
            *(bf16x8*)&sm[R_CND + (kb * 64 + lane) * 8] = pk;
        }
    }
    __syncthreads();

    // ---- input 1x1 conv: h0 = Win @ x + ib ----
    f32x4 hres[4];
    {
        f32x4 acc[4];
#pragma unroll
        for (int mt = 0; mt < 4; ++mt) acc[mt] = (f32x4){0.f, 0.f, 0.f, 0.f};
        gemm<8, 4, 8>(wp + IN_OFF + woff, sm, R_X + tl * 8, lg, acc);
#pragma unroll
        for (int mt = 0; mt < 4; ++mt) {
            int chb = wm * 64 + mt * 16 + lg * 4;
            f32x4 bv = {ib[chb], ib[chb + 1], ib[chb + 2], ib[chb + 3]};
            hres[mt] = acc[mt] + bv;
        }
    }
    __syncthreads();   // R_X reads done before R_HD/R_OUT reuse
#pragma unroll
    for (int mt = 0; mt < 4; ++mt) {
        int k0 = wm * 64 + mt * 16 + lg * 4;
        int kb = k0 >> 3, e0 = k0 & 7;
        s16x4 pk = {f2bf(hres[mt][0]), f2bf(hres[mt][1]), f2bf(hres[mt][2]), f2bf(hres[mt][3])};
        *(s16x4*)&sm[R_HT + (kb * 64 + tl) * 8 + e0] = pk;
        float* hp = hb0 + ((size_t)(b * 128 + k0)) * T_LEN + tg;
        st_cg(hp, hres[mt][0]); st_cg(hp + T_LEN, hres[mt][1]);
        st_cg(hp + 2 * T_LEN, hres[mt][2]); st_cg(hp + 3 * T_LEN, hres[mt][3]);
    }
    asm volatile("s_waitcnt vmcnt(0)" ::: "memory");
    __syncthreads();
    if (tid == 0) st_flag(&rdy[bidx], 1);   // h^0 ready

    f32x4 skp[4];
#pragma unroll
    for (int mt = 0; mt < 4; ++mt) skp[mt] = (f32x4){0.f, 0.f, 0.f, 0.f};

    // ---- 30 layers, p2p-synced ----
    for (int li = 0; li < NLAYER; ++li) {
        const float* hc = (li & 1) ? hb1 : hb0;
        float* hn       = (li & 1) ? hb0 : hb1;
        const int d = 1 << (li % 10);
        const int ksh = (d + 63) >> 6;           // src tile distance
        if (tid == 0) {
            int src = ti - ksh;
            if (src >= 0) wait_flag(&rdy[li * NTILES + b * NTPB + src]);
        }
        __syncthreads();                         // B1: flag seen; R_HD free
        {   // stage h[t-d] (LLC-coherent loads)
            const int ts = t0 - d + lane;
            const float* hsrc = hc + (size_t)b * 128 * T_LEN + ts;
#pragma unroll
            for (int it = 0; it < 2; ++it) {
                int kb = w * 2 + it;             // 0..15
                bf16x8 pk;
#pragma unroll
                for (int e = 0; e < 8; ++e) {
                    float v = 0.f;
                    if (ts >= 0) v = ld_cg(&hsrc[(size_t)(kb * 8 + e) * T_LEN]);
                    pk[e] = f2bf(v);
                }
                *(bf16x8*)&sm[R_HD + (kb * 64 + lane) * 8] = pk;
            }
        }
        __syncthreads();                         // B2: staging complete
        if (tid == 0) st_flag(&dn[li * NTILES + bidx], 1);

        const short* wl = wp + (size_t)li * LAYER_STRIDE;
        f32x4 aa[4], ag[4];
#pragma unroll
        for (int mt = 0; mt < 4; ++mt) { aa[mt] = (f32x4){0.f,0.f,0.f,0.f}; ag[mt] = (f32x4){0.f,0.f,0.f,0.f}; }
        gemm<4, 4, 8>(wl + 0  * 4096 + woff, sm, R_HD  + tl * 8, lg, aa); // Wd0 @ h[t-d]
        gemm<4, 4, 8>(wl + 4  * 4096 + woff, sm, R_HT  + tl * 8, lg, aa); // Wd1 @ h[t]
        gemm<3, 4, 8>(wl + 8  * 4096 + woff, sm, R_CND + tl * 8, lg, aa); // Wc @ cond (+bias)
        gemm<4, 4, 8>(wl + 11 * 4096 + woff, sm, R_HT  + tl * 8, lg, ag); // Wg @ h[t]
        gemm<3, 4, 8>(wl + 15 * 4096 + woff, sm, R_CND + tl * 8, lg, ag); // Wcg @ cond (+bias)
#pragma unroll
        for (int mt = 0; mt < 4; ++mt) {
            int k0 = wm * 64 + mt * 16 + lg * 4;
            int kb = k0 >> 3, e0 = k0 & 7;
            s16x4 pk;
#pragma unroll
            for (int j = 0; j < 4; ++j) pk[j] = f2bf(gated_act(aa[mt][j], ag[mt][j]));
            *(s16x4*)&sm[R_OUT + (kb * 64 + tl) * 8 + e0] = pk;
        }
        __syncthreads();                         // B3: out tile visible
        const float* rbl = rbias + li * 128;
        const float* sbl = sbias + li * 128;
        f32x4 ar[4], as2[4];
#pragma unroll
        for (int mt = 0; mt < 4; ++mt) { ar[mt] = (f32x4){0.f,0.f,0.f,0.f}; as2[mt] = (f32x4){0.f,0.f,0.f,0.f}; }
        gemm<4, 4, 8>(wl + 18 * 4096 + woff, sm, R_OUT + tl * 8, lg, ar);  // Wr @ out
        gemm<4, 4, 8>(wl + 22 * 4096 + woff, sm, R_OUT + tl * 8, lg, as2); // Ws @ out
#pragma unroll
        for (int mt = 0; mt < 4; ++mt) {
            int chb = wm * 64 + mt * 16 + lg * 4;
            f32x4 rbv = {rbl[chb], rbl[chb+1], rbl[chb+2], rbl[chb+3]};
            f32x4 sbv = {sbl[chb], sbl[chb+1], sbl[chb+2], sbl[chb+3]};
            hres[mt] = (hres[mt] + ar[mt] + rbv) * INV_SQRT2;
            skp[mt]  = skp[mt] + as2[mt] + sbv;
        }
        if (li < NLAYER - 1) {
#pragma unroll
            for (int mt = 0; mt < 4; ++mt) {     // new h -> s_ht (safe post-B3)
                int k0 = wm * 64 + mt * 16 + lg * 4;
                int kb = k0 >> 3, e0 = k0 & 7;
                s16x4 pk = {f2bf(hres[mt][0]), f2bf(hres[mt][1]), f2bf(hres[mt][2]), f2bf(hres[mt][3])};
                *(s16x4*)&sm[R_HT + (kb * 64 + tl) * 8 + e0] = pk;
            }
            if (tid == 0 && li >= 1) {           // WAR: reader of h^{li-1} staged?
                int d2 = 1 << ((li - 1) % 10);
                int r = ti + ((d2 + 63) >> 6);
                if (r < NTPB) wait_flag(&dn[(li - 1) * NTILES + b * NTPB + r]);
            }
            __syncthreads();                     // B4
#pragma unroll
            for (int mt = 0; mt < 4; ++mt) {
                int k0 = wm * 64 + mt * 16 + lg * 4;
                float* hp = hn + ((size_t)(b * 128 + k0)) * T_LEN + tg;
                st_cg(hp, hres[mt][0]); st_cg(hp + T_LEN, hres[mt][1]);
                st_cg(hp + 2 * T_LEN, hres[mt][2]); st_cg(hp + 3 * T_LEN, hres[mt][3]);
            }
            asm volatile("s_waitcnt vmcnt(0)" ::: "memory");
            __syncthreads();                     // B5: all stores at LLC
            if (tid == 0) st_flag(&rdy[(li + 1) * NTILES + bidx], 1);
        }
    }

    // ---- output head ----
    __syncthreads();
#pragma unroll
    for (int mt = 0; mt < 4; ++mt) {             // skip -> R_HD bf16
        int k0 = wm * 64 + mt * 16 + lg * 4;
        int kb = k0 >> 3, e0 = k0 & 7;
        s16x4 pk = {f2bf(skp[mt][0]), f2bf(skp[mt][1]), f2bf(skp[mt][2]), f2bf(skp[mt][3])};
        *(s16x4*)&sm[R_HD + (kb * 64 + tl) * 8 + e0] = pk;
    }
    __syncthreads();
    f32x4 ay[4];
#pragma unroll
    for (int mt = 0; mt < 4; ++mt) ay[mt] = (f32x4){0.f,0.f,0.f,0.f};
    gemm<4, 4, 8>(wp + OUT1_OFF + woff, sm, R_HD + tl * 8, lg, ay);
#pragma unroll
    for (int mt = 0; mt < 4; ++mt) {             // y = relu(. + b1) -> R_OUT
        int chb = wm * 64 + mt * 16 + lg * 4;
        int kb = chb >> 3, e0 = chb & 7;
        s16x4 pk;
#pragma unroll
        for (int j = 0; j < 4; ++j) pk[j] = f2bf(fmaxf(ay[mt][j] + b1[chb + j], 0.f));
        *(s16x4*)&sm[R_OUT + (kb * 64 + tl) * 8 + e0] = pk;
    }
    __syncthreads();
    f32x4 ao[8];
#pragma unroll
    for (int mt = 0; mt < 8; ++mt) ao[mt] = (f32x4){0.f,0.f,0.f,0.f};
    gemm<4, 8, 16>(wp + OUT2_OFF + (wm * 8) * 512 + lane * 8, sm, R_OUT + tl * 8, lg, ao);
#pragma unroll
    for (int mt = 0; mt < 8; ++mt) {
        int ch2 = wm * 128 + mt * 16 + lg * 4;
        float* op = outp + ((size_t)(b * 256 + ch2)) * T_LEN + tg;
        op[0]         = ao[mt][0] + b2[ch2];
        op[T_LEN]     = ao[mt][1] + b2[ch2 + 1];
        op[2 * T_LEN] = ao[mt][2] + b2[ch2 + 2];
        op[3 * T_LEN] = ao[mt][3] + b2[ch2 + 3];
    }
}

extern "C" void kernel_launch(void* const* d_in, const int* in_sizes, int n_in,
                              void* d_out, int out_size, void* d_ws, size_t ws_size,
                              hipStream_t stream)
{
    const float* x       = (const float*)d_in[0];
    const float* cond    = (const float*)d_in[1];
    const float* input_w = (const float*)d_in[2];
    const float* input_b = (const float*)d_in[3];
    const float* dil_w   = (const float*)d_in[4];
    const float* dil_b   = (const float*)d_in[5];
    const float* gate_w  = (const float*)d_in[6];
    const float* gate_b  = (const float*)d_in[7];
    const float* cond_w  = (const float*)d_in[8];
    const float* cond_b  = (const float*)d_in[9];
    const float* condg_w = (const float*)d_in[10];
    const float* condg_b = (const float*)d_in[11];
    const float* res_w   = (const float*)d_in[12];
    const float* res_b   = (const float*)d_in[13];
    const float* skip_w  = (const float*)d_in[14];
    const float* skip_b  = (const float*)d_in[15];
    const float* out1_w  = (const float*)d_in[16];
    const float* out1_b  = (const float*)d_in[17];
    const float* out2_w  = (const float*)d_in[18];
    const float* out2_b  = (const float*)d_in[19];
    float* outp = (float*)d_out;
    float* ws   = (float*)d_ws;

    const size_t ACT = (size_t)2 * 128 * T_LEN;
    float* hb0 = ws;
    float* hb1 = hb0 + ACT;
    short* wpk = (short*)(hb1 + ACT);             // 6400*512 shorts
    int* rdy   = (int*)(wpk + (size_t)6400 * 512);
    int* dn    = rdy + NLAYER * NTILES;

    k_pack<<<1600, 256, 0, stream>>>(dil_w, gate_w, cond_w, condg_w, res_w, skip_w,
                                     input_w, out1_w, out2_w,
                                     dil_b, cond_b, gate_b, condg_b, wpk, rdy, dn);

    void* args[] = {(void*)&x, (void*)&cond, (void*)&wpk, (void*)&hb0, (void*)&hb1,
                    (void*)&input_b, (void*)&res_b, (void*)&skip_b,
                    (void*)&out1_b, (void*)&out2_b, (void*)&outp,
                    (void*)&rdy, (void*)&dn};
    hipLaunchCooperativeKernel((void*)k_wavenet, dim3(NBLK), dim3(512), args, 0, stream);
}

// Round 5
// 385.489 us; speedup vs baseline: 13.4106x; 1.0391x over previous
//
#include <hip/hip_runtime.h>

#define T_LEN 8000
#define NTPB 125
#define NBLK 250
#define NTILES 250
#define NLAYER 30
#define GUARD 512
#define HROWS (GUARD + T_LEN)
#define SLAB (HROWS * 128)           // shorts per (buf,batch) h slab
#define INV_SQRT2 0.70710678118f

typedef short bf16x8 __attribute__((ext_vector_type(8)));
typedef unsigned uint2v __attribute__((ext_vector_type(2)));
typedef unsigned uint4v __attribute__((ext_vector_type(4)));
typedef float f32x4 __attribute__((ext_vector_type(4)));

// LDS regions (shorts). [kb][t][8] layout, kb-slot = 512 shorts (64t x 8ch)
#define R_HT   0        // h[t] bf16, 16 kb-slots (16 KB)
#define R_OUT  8192     // gated out / y in head (16 KB)
#define R_X    8192     // input x tile, 32 kb-slots (32 KB, overlays R_OUT+spare)
#define R_CND  24576    // cond tile, 12 kb-slots (k=80 -> 1.0 bias col)
#define LDS_SHORTS 30720

#define LAYER_STRIDE 106496   // 26 k-lines * 8 frags * 512 shorts
#define IN_OFF   3194880
#define OUT1_OFF 3227648
#define OUT2_OFF 3244032

__device__ __forceinline__ unsigned short f2bf_u(float f) {
    union { float f; unsigned u; } v; v.f = f;
    unsigned u = v.u + 0x7FFFu + ((v.u >> 16) & 1u);
    return (unsigned short)(u >> 16);
}
__device__ __forceinline__ short f2bf(float f) { return (short)f2bf_u(f); }

__device__ __forceinline__ unsigned cvtpk(float lo, float hi) {
    unsigned r;
    asm("v_cvt_pk_bf16_f32 %0, %1, %2" : "=v"(r) : "v"(lo), "v"(hi));
    return r;
}

__device__ __forceinline__ float gated_act(float av, float gv) {
    float e  = __expf(-2.f * fabsf(av));
    float th = (1.f - e) * __builtin_amdgcn_rcpf(1.f + e);
    th = (av < 0.f) ? -th : th;
    float sg = __builtin_amdgcn_rcpf(1.f + __expf(-gv));
    return th * sg;
}

// agent-scope (LLC-coherent) primitives
__device__ __forceinline__ void ldg16_sc1(bf16x8* d, const short* p) {
    asm volatile("global_load_dwordx4 %0, %1, off sc1" : "=v"(*d) : "v"(p));
}
__device__ __forceinline__ void stg8_sc1(short* p, uint2v v) {
    asm volatile("global_store_dwordx2 %0, %1, off sc1" : : "v"(p), "v"(v) : "memory");
}
__device__ __forceinline__ void st_flag(int* p, int v) {
    __hip_atomic_store(p, v, __ATOMIC_RELAXED, __HIP_MEMORY_SCOPE_AGENT);
}
__device__ __forceinline__ void wait_flag(const int* p) {
    while (__hip_atomic_load(p, __ATOMIC_RELAXED, __HIP_MEMORY_SCOPE_AGENT) == 0)
        __builtin_amdgcn_s_sleep(2);
}

__device__ __forceinline__ f32x4 mfma_(bf16x8 a, bf16x8 b, f32x4 c) {
    return __builtin_amdgcn_mfma_f32_16x16x32_bf16(a, b, c, 0, 0, 0);
}

// one A-stream gemm: B from LDS [kb][t][8]
template<int NK, int MT, int KSP>
__device__ __forceinline__ void gemm1(const short* __restrict__ wb, const short* sm,
                                      int boff, int lg, f32x4* acc)
{
#pragma unroll
    for (int ks = 0; ks < NK; ++ks) {
        bf16x8 B = *(const bf16x8*)&sm[boff + (ks * 4 + lg) * 512];
#pragma unroll
        for (int mt = 0; mt < MT; ++mt) {
            bf16x8 A = *(const bf16x8*)&wb[(ks * KSP + mt) * 512];
            acc[mt] = mfma_(A, B, acc[mt]);
        }
    }
}

// two A-streams sharing one B read
template<int NK>
__device__ __forceinline__ void gemm2(const short* __restrict__ wb0,
                                      const short* __restrict__ wb1,
                                      const short* sm, int boff, int lg,
                                      f32x4* acA, f32x4* acB)
{
#pragma unroll
    for (int ks = 0; ks < NK; ++ks) {
        bf16x8 B = *(const bf16x8*)&sm[boff + (ks * 4 + lg) * 512];
#pragma unroll
        for (int mt = 0; mt < 2; ++mt) {
            bf16x8 a0 = *(const bf16x8*)&wb0[(ks * 8 + mt) * 512];
            acA[mt] = mfma_(a0, B, acA[mt]);
            bf16x8 a1 = *(const bf16x8*)&wb1[(ks * 8 + mt) * 512];
            acB[mt] = mfma_(a1, B, acB[mt]);
        }
    }
}

// ---------------- weight pack + flag/guard zero ----------------
__global__ __launch_bounds__(256) void k_pack(
    const float* __restrict__ dil_w, const float* __restrict__ gate_w,
    const float* __restrict__ cond_w, const float* __restrict__ condg_w,
    const float* __restrict__ res_w, const float* __restrict__ skip_w,
    const float* __restrict__ input_w, const float* __restrict__ out1_w,
    const float* __restrict__ out2_w,
    const float* __restrict__ dil_b, const float* __restrict__ cond_b,
    const float* __restrict__ gate_b, const float* __restrict__ condg_b,
    short* __restrict__ wp, short* __restrict__ hbt, int* __restrict__ flg)
{
    int gid = blockIdx.x * 256 + threadIdx.x;
    if (gid < 16384) flg[gid] = 0;
    {
        int g2 = gid - 16384;
        if (g2 >= 0 && g2 < 131072) {           // zero guard rows of 4 h slabs
            unsigned* hb32 = (unsigned*)hbt;
            int slab = g2 >> 15, off = g2 & 32767;
            hb32[(size_t)slab * (SLAB / 2) + off] = 0u;
        }
    }
    if (gid >= 6400 * 64) return;
    int fid = gid >> 6, lane = gid & 63;
    int lr = lane & 15, lg = lane >> 4;
    float v[8];
    if (fid < 6240) {
        int layer = fid / 208;
        int r = fid - layer * 208;
        int kl = r >> 3, mt = r & 7;
        int m = mt * 16 + lr;
        int mi = layer * 128 + m;
        int seg, ks;
        if      (kl < 4)  { seg = 0; ks = kl;      }
        else if (kl < 8)  { seg = 1; ks = kl - 4;  }
        else if (kl < 11) { seg = 2; ks = kl - 8;  }
        else if (kl < 15) { seg = 3; ks = kl - 11; }
        else if (kl < 18) { seg = 4; ks = kl - 15; }
        else if (kl < 22) { seg = 5; ks = kl - 18; }
        else              { seg = 6; ks = kl - 22; }
        int kb = ks * 32 + lg * 8;
#pragma unroll
        for (int e = 0; e < 8; ++e) {
            int k = kb + e;
            float val;
            switch (seg) {
                case 0:  val = dil_w[((size_t)mi * 128 + k) * 2];     break;
                case 1:  val = dil_w[((size_t)mi * 128 + k) * 2 + 1]; break;
                case 2:  val = (k < 80) ? cond_w[(size_t)mi * 80 + k]
                               : ((k == 80) ? dil_b[mi] + cond_b[mi] : 0.f); break;
                case 3:  val = gate_w[(size_t)mi * 128 + k]; break;
                case 4:  val = (k < 80) ? condg_w[(size_t)mi * 80 + k]
                               : ((k == 80) ? gate_b[mi] + condg_b[mi] : 0.f); break;
                case 5:  val = res_w[(size_t)mi * 128 + k]; break;
                default: val = skip_w[(size_t)mi * 128 + k]; break;
            }
            v[e] = val;
        }
    } else if (fid < 6304) {
        int f = fid - 6240; int ks = f >> 3, mt = f & 7;
        int m = mt * 16 + lr; int kb = ks * 32 + lg * 8;
#pragma unroll
        for (int e = 0; e < 8; ++e) v[e] = input_w[(size_t)m * 256 + kb + e];
    } else if (fid < 6336) {
        int f = fid - 6304; int ks = f >> 3, mt = f & 7;
        int m = mt * 16 + lr; int kb = ks * 32 + lg * 8;
#pragma unroll
        for (int e = 0; e < 8; ++e) v[e] = out1_w[(size_t)m * 128 + kb + e];
    } else {
        int f = fid - 6336; int ks = f >> 4, mt = f & 15;
        int m = mt * 16 + lr; int kb = ks * 32 + lg * 8;
#pragma unroll
        for (int e = 0; e < 8; ++e) v[e] = out2_w[(size_t)m * 128 + kb + e];
    }
    short* dst = wp + (size_t)fid * 512 + lane * 8;
#pragma unroll
    for (int e = 0; e < 8; ++e) dst[e] = f2bf(v[e]);
}

// ---------------- persistent fused WaveNet ----------------
__global__ __launch_bounds__(1024, 4) void k_wavenet(
    const float* __restrict__ x, const float* __restrict__ cond,
    const short* __restrict__ wp, short* __restrict__ hbt,
    const float* __restrict__ ib, const float* __restrict__ rbias,
    const float* __restrict__ sbias, const float* __restrict__ b1,
    const float* __restrict__ b2, float* __restrict__ outp,
    int* __restrict__ rdy, int* __restrict__ dn)
{
    __shared__ short sm[LDS_SHORTS];   // 60 KB

    const int tid  = threadIdx.x;
    const int lane = tid & 63;
    const int wv   = __builtin_amdgcn_readfirstlane(tid >> 6);   // 0..15
    const int wm   = wv & 3;            // ch group: base = wm*32 (2 frags)
    const int wn   = wv >> 2;           // t group: base = wn*16
    const int lr   = lane & 15, lg = lane >> 4;
    const int bidx = blockIdx.x;
    const int b    = bidx / NTPB;
    const int ti   = bidx - b * NTPB;
    const int t0   = ti * 64;
    const int tl   = wn * 16 + lr;
    const int tg   = t0 + tl;
    const int tl8  = tl * 8;
    const int chA  = wm * 32 + lg * 4;            // + mt*16 : accumulator ch base
    const int kbA  = wm * 4 + (lg >> 1);          // + mt*2  : LDS kb-slot
    const int e0   = (lg & 1) * 4;

    // ---- stage x (32 kb-slots) and cond (12 kb-slots, k=80 -> 1.0) ----
    {
        const float* xb = x + (size_t)b * 256 * T_LEN + t0 + lane;
#pragma unroll
        for (int it = 0; it < 2; ++it) {
            int kb = (tid >> 6) * 2 + it;         // 0..31
            unsigned pk[4];
#pragma unroll
            for (int e = 0; e < 4; ++e)
                pk[e] = cvtpk(xb[(size_t)(kb * 8 + 2 * e) * T_LEN],
                              xb[(size_t)(kb * 8 + 2 * e + 1) * T_LEN]);
            *(uint4v*)&sm[R_X + (kb * 64 + lane) * 8] = *(uint4v*)pk;
        }
        int w16 = tid >> 6;
        if (w16 < 12) {
            const float* cb = cond + (size_t)b * 80 * T_LEN + t0 + lane;
            unsigned pk[4];
#pragma unroll
            for (int e = 0; e < 4; ++e) {
                int c0 = w16 * 8 + 2 * e, c1 = c0 + 1;
                float v0 = (c0 < 80) ? cb[(size_t)c0 * T_LEN] : ((c0 == 80) ? 1.f : 0.f);
                float v1 = (c1 < 80) ? cb[(size_t)c1 * T_LEN] : 0.f;
                pk[e] = cvtpk(v0, v1);
            }
            *(uint4v*)&sm[R_CND + (w16 * 64 + lane) * 8] = *(uint4v*)pk;
        }
    }
    __syncthreads();

    // ---- input conv: h0 = Win @ x + ib ----
    f32x4 hres[2];
    {
        f32x4 acc[2] = {(f32x4){0.f,0.f,0.f,0.f}, (f32x4){0.f,0.f,0.f,0.f}};
        gemm1<8, 2, 8>(wp + IN_OFF + (wm * 2) * 512 + lane * 8, sm, R_X + tl8, lg, acc);
        hres[0] = acc[0] + (f32x4){ib[chA], ib[chA+1], ib[chA+2], ib[chA+3]};
        hres[1] = acc[1] + (f32x4){ib[chA+16], ib[chA+17], ib[chA+18], ib[chA+19]};
    }
    {
        short* hrow = hbt + (size_t)b * SLAB + (size_t)(GUARD + tg) * 128 + chA;
#pragma unroll
        for (int mt = 0; mt < 2; ++mt) {
            uint2v hv = {cvtpk(hres[mt][0], hres[mt][1]), cvtpk(hres[mt][2], hres[mt][3])};
            stg8_sc1(hrow + mt * 16, hv);
            *(uint2v*)&sm[R_HT + ((kbA + mt * 2) * 64 + tl) * 8 + e0] = hv;
        }
    }
    asm volatile("s_waitcnt vmcnt(0)" ::: "memory");
    __syncthreads();
    if (tid == 0) st_flag(&rdy[bidx], 1);    // h^0 ready

    f32x4 skp[2] = {(f32x4){0.f,0.f,0.f,0.f}, (f32x4){0.f,0.f,0.f,0.f}};

    // ---- 30 layers ----
    for (int li = 0; li < NLAYER; ++li) {
        const int d   = 1 << (li % 10);
        const int ksh = (d + 63) >> 6;
        const short* hcb = hbt + (size_t)((li & 1) * 2 + b) * SLAB;
        short*       hnb = hbt + (size_t)(((li + 1) & 1) * 2 + b) * SLAB;
        const short* wl  = wp + (size_t)li * LAYER_STRIDE + (wm * 2) * 512 + lane * 8;

        // prefetch Wd0 A-frags (independent of flag)
        bf16x8 A0[4][2];
#pragma unroll
        for (int ks = 0; ks < 4; ++ks)
#pragma unroll
            for (int mt = 0; mt < 2; ++mt)
                A0[ks][mt] = *(const bf16x8*)&wl[(ks * 8 + mt) * 512];

        // phase 1: everything not needing h[t-d]
        f32x4 aa[2] = {(f32x4){0.f,0.f,0.f,0.f}, (f32x4){0.f,0.f,0.f,0.f}};
        f32x4 ag[2] = {(f32x4){0.f,0.f,0.f,0.f}, (f32x4){0.f,0.f,0.f,0.f}};
        gemm2<4>(wl + 4 * 4096, wl + 11 * 4096, sm, R_HT + tl8, lg, aa, ag);   // Wd1,Wg @ h[t]
        gemm2<3>(wl + 8 * 4096, wl + 15 * 4096, sm, R_CND + tl8, lg, aa, ag);  // Wc,Wcg @ cond+bias

        // dependency: h[t-d] direct from global (LLC-coherent)
        if (lane == 0 && ti >= ksh)
            wait_flag(&rdy[li * NTILES + b * NTPB + ti - ksh]);
        bf16x8 Bg[4];
        const short* hr = hcb + (size_t)(GUARD + tg - d) * 128 + lg * 8;
#pragma unroll
        for (int ks = 0; ks < 4; ++ks) ldg16_sc1(&Bg[ks], hr + ks * 32);
        asm volatile("s_waitcnt vmcnt(0)" ::: "memory");
        __builtin_amdgcn_sched_barrier(0);
#pragma unroll
        for (int ks = 0; ks < 4; ++ks)
#pragma unroll
            for (int mt = 0; mt < 2; ++mt)
                aa[mt] = mfma_(A0[ks][mt], Bg[ks], aa[mt]);

        // out = tanh(a)*sigmoid(g) -> R_OUT
#pragma unroll
        for (int mt = 0; mt < 2; ++mt) {
            uint2v ov = {cvtpk(gated_act(aa[mt][0], ag[mt][0]), gated_act(aa[mt][1], ag[mt][1])),
                         cvtpk(gated_act(aa[mt][2], ag[mt][2]), gated_act(aa[mt][3], ag[mt][3]))};
            *(uint2v*)&sm[R_OUT + ((kbA + mt * 2) * 64 + tl) * 8 + e0] = ov;
        }
        __syncthreads();                                  // B3
        if (tid == 0 && li < NLAYER - 1) st_flag(&dn[li * NTILES + bidx], 1);

        f32x4 ar[2]  = {(f32x4){0.f,0.f,0.f,0.f}, (f32x4){0.f,0.f,0.f,0.f}};
        f32x4 as2[2] = {(f32x4){0.f,0.f,0.f,0.f}, (f32x4){0.f,0.f,0.f,0.f}};
        gemm2<4>(wl + 18 * 4096, wl + 22 * 4096, sm, R_OUT + tl8, lg, ar, as2); // Wr,Ws @ out

        const float* rbl = rbias + li * 128 + chA;
        const float* sbl = sbias + li * 128 + chA;
#pragma unroll
        for (int mt = 0; mt < 2; ++mt) {
            f32x4 rbv = {rbl[mt*16], rbl[mt*16+1], rbl[mt*16+2], rbl[mt*16+3]};
            f32x4 sbv = {sbl[mt*16], sbl[mt*16+1], sbl[mt*16+2], sbl[mt*16+3]};
            hres[mt] = (hres[mt] + ar[mt] + rbv) * INV_SQRT2;
            skp[mt]  = skp[mt] + as2[mt] + sbv;
        }

        if (li < NLAYER - 1) {
            if (lane == 0 && li >= 1) {        // WAR: reader of h^{li-1} done with our rows?
                int dp = 1 << ((li - 1) % 10);
                int r = ti + ((dp + 63) >> 6);
                if (r < NTPB) wait_flag(&dn[(li - 1) * NTILES + b * NTPB + r]);
            }
            short* hrow = hnb + (size_t)(GUARD + tg) * 128 + chA;
#pragma unroll
            for (int mt = 0; mt < 2; ++mt) {
                uint2v hv = {cvtpk(hres[mt][0], hres[mt][1]), cvtpk(hres[mt][2], hres[mt][3])};
                stg8_sc1(hrow + mt * 16, hv);
                *(uint2v*)&sm[R_HT + ((kbA + mt * 2) * 64 + tl) * 8 + e0] = hv;
            }
            asm volatile("s_waitcnt vmcnt(0)" ::: "memory");
        }
        __syncthreads();                                  // B4
        if (tid == 0 && li < NLAYER - 1) st_flag(&rdy[(li + 1) * NTILES + bidx], 1);
    }

    // ---- output head ----
#pragma unroll
    for (int mt = 0; mt < 2; ++mt) {          // skip -> R_HT
        uint2v sv = {cvtpk(skp[mt][0], skp[mt][1]), cvtpk(skp[mt][2], skp[mt][3])};
        *(uint2v*)&sm[R_HT + ((kbA + mt * 2) * 64 + tl) * 8 + e0] = sv;
    }
    __syncthreads();
    f32x4 ay[2] = {(f32x4){0.f,0.f,0.f,0.f}, (f32x4){0.f,0.f,0.f,0.f}};
    gemm1<4, 2, 8>(wp + OUT1_OFF + (wm * 2) * 512 + lane * 8, sm, R_HT + tl8, lg, ay);
#pragma unroll
    for (int mt = 0; mt < 2; ++mt) {          // y = relu(. + b1) -> R_OUT
        float y0 = fmaxf(ay[mt][0] + b1[chA + mt*16],     0.f);
        float y1 = fmaxf(ay[mt][1] + b1[chA + mt*16 + 1], 0.f);
        float y2 = fmaxf(ay[mt][2] + b1[chA + mt*16 + 2], 0.f);
        float y3 = fmaxf(ay[mt][3] + b1[chA + mt*16 + 3], 0.f);
        uint2v yv = {cvtpk(y0, y1), cvtpk(y2, y3)};
        *(uint2v*)&sm[R_OUT + ((kbA + mt * 2) * 64 + tl) * 8 + e0] = yv;
    }
    __syncthreads();
    f32x4 ao[4] = {(f32x4){0.f,0.f,0.f,0.f}, (f32x4){0.f,0.f,0.f,0.f},
                   (f32x4){0.f,0.f,0.f,0.f}, (f32x4){0.f,0.f,0.f,0.f}};
    gemm1<4, 4, 16>(wp + OUT2_OFF + (wm * 4) * 512 + lane * 8, sm, R_OUT + tl8, lg, ao);
#pragma unroll
    for (int mt = 0; mt < 4; ++mt) {
        int ch2 = wm * 64 + mt * 16 + lg * 4;
        float* op = outp + ((size_t)(b * 256 + ch2)) * T_LEN + tg;
        op[0]         = ao[mt][0] + b2[ch2];
        op[T_LEN]     = ao[mt][1] + b2[ch2 + 1];
        op[2 * T_LEN] = ao[mt][2] + b2[ch2 + 2];
        op[3 * T_LEN] = ao[mt][3] + b2[ch2 + 3];
    }
}

extern "C" void kernel_launch(void* const* d_in, const int* in_sizes, int n_in,
                              void* d_out, int out_size, void* d_ws, size_t ws_size,
                              hipStream_t stream)
{
    const float* x       = (const float*)d_in[0];
    const float* cond    = (const float*)d_in[1];
    const float* input_w = (const float*)d_in[2];
    const float* input_b = (const float*)d_in[3];
    const float* dil_w   = (const float*)d_in[4];
    const float* dil_b   = (const float*)d_in[5];
    const float* gate_w  = (const float*)d_in[6];
    const float* gate_b  = (const float*)d_in[7];
    const float* cond_w  = (const float*)d_in[8];
    const float* cond_b  = (const float*)d_in[9];
    const float* condg_w = (const float*)d_in[10];
    const float* condg_b = (const float*)d_in[11];
    const float* res_w   = (const float*)d_in[12];
    const float* res_b   = (const float*)d_in[13];
    const float* skip_w  = (const float*)d_in[14];
    const float* skip_b  = (const float*)d_in[15];
    const float* out1_w  = (const float*)d_in[16];
    const float* out1_b  = (const float*)d_in[17];
    const float* out2_w  = (const float*)d_in[18];
    const float* out2_b  = (const float*)d_in[19];
    float* outp = (float*)d_out;

    short* wpk = (short*)d_ws;                        // 6400*512 shorts
    short* hbt = wpk + (size_t)6400 * 512;            // 4 slabs bf16
    int*   flg = (int*)(hbt + (size_t)4 * SLAB);      // 16384 ints
    int*   rdy = flg;
    int*   dn  = flg + 8192;

    k_pack<<<1600, 256, 0, stream>>>(dil_w, gate_w, cond_w, condg_w, res_w, skip_w,
                                     input_w, out1_w, out2_w,
                                     dil_b, cond_b, gate_b, condg_b, wpk, hbt, flg);

    void* args[] = {(void*)&x, (void*)&cond, (void*)&wpk, (void*)&hbt,
                    (void*)&input_b, (void*)&res_b, (void*)&skip_b,
                    (void*)&out1_b, (void*)&out2_b, (void*)&outp,
                    (void*)&rdy, (void*)&dn};
    hipLaunchCooperativeKernel((void*)k_wavenet, dim3(NBLK), dim3(1024), args, 0, stream);
}

// Round 6
// 289.458 us; speedup vs baseline: 17.8597x; 1.3318x over previous
//
#include <hip/hip_runtime.h>

#define T_LEN 8000
#define NTPB 125
#define NBLK 250
#define NLAYER 30
#define GUARD 512
#define HROWS (GUARD + T_LEN)
#define SLAB (HROWS * 128)          // shorts per h slab (level,batch)
#define INV_SQRT2 0.70710678118f

typedef short bf16x8 __attribute__((ext_vector_type(8)));
typedef unsigned uint2v __attribute__((ext_vector_type(2)));
typedef unsigned uint4v __attribute__((ext_vector_type(4)));
typedef float f32x4 __attribute__((ext_vector_type(4)));

// ---- LDS layout (shorts). [kb][t][8] slots, slot = 512 shorts ----
#define R_HT  0          // h[t] (16 slots) ; x tile spans R_HT+R_OUT (32 slots)
#define R_OUT 8192       // gated out / y
#define R_CND 16384      // cond (12 slots; k=80 -> 1.0 bias col)
#define WB0   22528      // weight stage buf 0 (16384 shorts = 32 KB)
#define WB1   38912      // weight stage buf 1
#define LDS_SHORTS 55296

// ---- weight pack (shorts): per layer 26 klines (kline = 8 frags x 512) ----
// kline order: [d1_0,g_0,d1_1,g_1, d1_2,g_2,d1_3,g_3, c_0,cg_0,c_1,cg_1, c_2,cg_2,
//               d0_0..3, r_0,s_0,r_1,s_1, r_2,s_2,r_3,s_3]
#define KLINE 4096
#define LS 106496
#define C1 16384
#define C2 32768
#define C3 49152
#define C4 57344
#define C5 73728
#define C6 90112
#define IN_OFF   3194880
#define OUT1_OFF 3227648
#define OUT2_OFF 3244032

__device__ __forceinline__ unsigned short f2bf_u(float f) {
    union { float f; unsigned u; } v; v.f = f;
    unsigned u = v.u + 0x7FFFu + ((v.u >> 16) & 1u);
    return (unsigned short)(u >> 16);
}
__device__ __forceinline__ short f2bf(float f) { return (short)f2bf_u(f); }

__device__ __forceinline__ unsigned cvtpk(float lo, float hi) {
    unsigned r;
    asm("v_cvt_pk_bf16_f32 %0, %1, %2" : "=v"(r) : "v"(lo), "v"(hi));
    return r;
}

__device__ __forceinline__ float gated_act(float av, float gv) {
    float e  = __expf(-2.f * fabsf(av));
    float th = (1.f - e) * __builtin_amdgcn_rcpf(1.f + e);
    th = (av < 0.f) ? -th : th;
    float sg = __builtin_amdgcn_rcpf(1.f + __expf(-gv));
    return th * sg;
}

__device__ __forceinline__ void ldg16_sc1(bf16x8* d, const short* p) {
    asm volatile("global_load_dwordx4 %0, %1, off sc1" : "=v"(*d) : "v"(p));
}
__device__ __forceinline__ void stg8_sc1(short* p, uint2v v) {
    asm volatile("global_store_dwordx2 %0, %1, off sc1" : : "v"(p), "v"(v) : "memory");
}
__device__ __forceinline__ void st_flag(int* p, int v) {
    __hip_atomic_store(p, v, __ATOMIC_RELAXED, __HIP_MEMORY_SCOPE_AGENT);
}
__device__ __forceinline__ void wait_ge(const int* p, int v) {
    while (__hip_atomic_load(p, __ATOMIC_RELAXED, __HIP_MEMORY_SCOPE_AGENT) < v)
        __builtin_amdgcn_s_sleep(1);
}

__device__ __forceinline__ f32x4 mfma_(bf16x8 a, bf16x8 b, f32x4 c) {
    return __builtin_amdgcn_mfma_f32_16x16x32_bf16(a, b, c, 0, 0, 0);
}

__device__ __forceinline__ void gload_lds16(const short* g, short* l) {
    __builtin_amdgcn_global_load_lds(
        (const __attribute__((address_space(1))) unsigned int*)g,
        (__attribute__((address_space(3))) unsigned int*)l, 16, 0, 0);
}
// stage a 32 KB chunk (2 issues/thread) / 16 KB chunk (1 issue)
__device__ __forceinline__ void stageW2(const short* src, short* dst, int wv, int lane) {
    gload_lds16(src + wv * 512 + lane * 8, dst + wv * 512);
    gload_lds16(src + (16 + wv) * 512 + lane * 8, dst + (16 + wv) * 512);
}
__device__ __forceinline__ void stageW1(const short* src, short* dst, int wv, int lane) {
    gload_lds16(src + wv * 512 + lane * 8, dst + wv * 512);
}

// two A-streams (matrix pair), B from LDS slot table
template<int NP>
__device__ __forceinline__ void pairN(const short* wb, const short* sm, int boff,
                                      int ks0, int lg, int awoff,
                                      f32x4* ac0, f32x4* ac1)
{
#pragma unroll
    for (int p = 0; p < NP; ++p) {
        bf16x8 B = *(const bf16x8*)&sm[boff + ((ks0 + p) * 4 + lg) * 512];
#pragma unroll
        for (int mt = 0; mt < 2; ++mt) {
            bf16x8 a0 = *(const bf16x8*)&wb[p * 8192 + awoff + mt * 512];
            ac0[mt] = mfma_(a0, B, ac0[mt]);
            bf16x8 a1 = *(const bf16x8*)&wb[p * 8192 + 4096 + awoff + mt * 512];
            ac1[mt] = mfma_(a1, B, ac1[mt]);
        }
    }
}
// single A-stream
template<int NP>
__device__ __forceinline__ void singleN(const short* wb, const short* sm, int boff,
                                        int ks0, int lg, int awoff, f32x4* ac)
{
#pragma unroll
    for (int p = 0; p < NP; ++p) {
        bf16x8 B = *(const bf16x8*)&sm[boff + ((ks0 + p) * 4 + lg) * 512];
#pragma unroll
        for (int mt = 0; mt < 2; ++mt) {
            bf16x8 a = *(const bf16x8*)&wb[p * 4096 + awoff + mt * 512];
            ac[mt] = mfma_(a, B, ac[mt]);
        }
    }
}

// ---------------- weight pack + flag/guard zero ----------------
__global__ __launch_bounds__(256) void k_pack(
    const float* __restrict__ dil_w, const float* __restrict__ gate_w,
    const float* __restrict__ cond_w, const float* __restrict__ condg_w,
    const float* __restrict__ res_w, const float* __restrict__ skip_w,
    const float* __restrict__ input_w, const float* __restrict__ out1_w,
    const float* __restrict__ out2_w,
    const float* __restrict__ dil_b, const float* __restrict__ cond_b,
    const float* __restrict__ gate_b, const float* __restrict__ condg_b,
    short* __restrict__ wp, short* __restrict__ hbt, int* __restrict__ flg)
{
    int gid = blockIdx.x * 256 + threadIdx.x;
    if (gid < 512) flg[gid] = 0;
    {
        int g2 = gid - 512;
        if (g2 >= 0 && g2 < 262144) {      // zero guard rows of 8 slabs
            unsigned* hb32 = (unsigned*)hbt;
            int slab = g2 >> 15, off = g2 & 32767;
            hb32[(size_t)slab * (SLAB / 2) + off] = 0u;
        }
    }
    if (gid >= 6400 * 64) return;
    int fid = gid >> 6, lane = gid & 63;
    int lr = lane & 15, lg = lane >> 4;
    float v[8];
    if (fid < 6240) {
        int layer = fid / 208;
        int r = fid - layer * 208;
        int kl = r >> 3, f = r & 7;
        int m = f * 16 + lr;
        size_t mi = (size_t)layer * 128 + m;
        int mat, ks;
        if      (kl < 8)  { mat = (kl & 1) ? 2 : 1; ks = kl >> 1; }        // g : d1
        else if (kl < 14) { mat = (kl & 1) ? 4 : 3; ks = (kl - 8) >> 1; }  // cg : c
        else if (kl < 18) { mat = 0; ks = kl - 14; }                       // d0
        else              { mat = (kl & 1) ? 6 : 5; ks = (kl - 18) >> 1; } // s : r
        int kb = ks * 32 + lg * 8;
#pragma unroll
        for (int e = 0; e < 8; ++e) {
            int k = kb + e;
            float val;
            switch (mat) {
                case 0:  val = dil_w[(mi * 128 + k) * 2];     break;
                case 1:  val = dil_w[(mi * 128 + k) * 2 + 1]; break;
                case 2:  val = gate_w[mi * 128 + k]; break;
                case 3:  val = (k < 80) ? cond_w[mi * 80 + k]
                               : ((k == 80) ? dil_b[mi] + cond_b[mi] : 0.f); break;
                case 4:  val = (k < 80) ? condg_w[mi * 80 + k]
                               : ((k == 80) ? gate_b[mi] + condg_b[mi] : 0.f); break;
                case 5:  val = res_w[mi * 128 + k]; break;
                default: val = skip_w[mi * 128 + k]; break;
            }
            v[e] = val;
        }
    } else if (fid < 6304) {               // input conv: 8 klines
        int f = fid - 6240; int ks = f >> 3, fr = f & 7;
        int m = fr * 16 + lr; int kb = ks * 32 + lg * 8;
#pragma unroll
        for (int e = 0; e < 8; ++e) v[e] = input_w[(size_t)m * 256 + kb + e];
    } else if (fid < 6336) {               // out1: 4 klines
        int f = fid - 6304; int ks = f >> 3, fr = f & 7;
        int m = fr * 16 + lr; int kb = ks * 32 + lg * 8;
#pragma unroll
        for (int e = 0; e < 8; ++e) v[e] = out1_w[(size_t)m * 128 + kb + e];
    } else {                               // out2: 8 klines (ks-major, half per kline)
        int f = fid - 6336; int mt = f & 15; int ks = f >> 4;
        int m = mt * 16 + lr; int kb = ks * 32 + lg * 8;
#pragma unroll
        for (int e = 0; e < 8; ++e) v[e] = out2_w[(size_t)m * 128 + kb + e];
    }
    short* dst = wp + (size_t)fid * 512 + lane * 8;
#pragma unroll
    for (int e = 0; e < 8; ++e) dst[e] = f2bf(v[e]);
}

// ---------------- persistent fused WaveNet ----------------
__global__ __launch_bounds__(1024, 4) void k_wavenet(
    const float* __restrict__ x, const float* __restrict__ cond,
    const short* __restrict__ wp, short* __restrict__ hbt,
    const float* __restrict__ ib, const float* __restrict__ rbias,
    const float* __restrict__ sbias, const float* __restrict__ b1,
    const float* __restrict__ b2, float* __restrict__ outp,
    int* __restrict__ rdy, int* __restrict__ dn)
{
    __shared__ __align__(16) short sm[LDS_SHORTS];   // 108 KB

    const int tid  = threadIdx.x;
    const int lane = tid & 63;
    const int wv   = __builtin_amdgcn_readfirstlane(tid >> 6);   // 0..15
    const int wm   = wv & 3;
    const int wn   = wv >> 2;
    const int lr   = lane & 15, lg = lane >> 4;
    const int bidx = blockIdx.x;
    const int b    = bidx / NTPB;
    const int ti   = bidx - b * NTPB;
    const int t0   = ti * 64;
    const int tl   = wn * 16 + lr;
    const int tg   = t0 + tl;
    const int tl8  = tl * 8;
    const int lane8 = lane * 8;
    const int awoff = wm * 1024 + lane8;
    const int chA  = wm * 32 + lg * 4;
    const int kbA  = wm * 4 + (lg >> 1);
    const int e0   = (lg & 1) * 4;

    // ---- stage input-conv weights + x tile (slots 0..31) + cond tile ----
    stageW2(wp + IN_OFF, (short*)&sm[WB0], wv, lane);
    stageW2(wp + IN_OFF + 16384, (short*)&sm[WB1], wv, lane);
    {
        const float* xb = x + (size_t)b * 256 * T_LEN + t0 + lane;
#pragma unroll
        for (int it = 0; it < 2; ++it) {
            int kb = wv * 2 + it;              // 0..31
            unsigned pk[4];
#pragma unroll
            for (int e = 0; e < 4; ++e)
                pk[e] = cvtpk(xb[(size_t)(kb * 8 + 2 * e) * T_LEN],
                              xb[(size_t)(kb * 8 + 2 * e + 1) * T_LEN]);
            *(uint4v*)&sm[(kb * 64 + lane) * 8] = *(uint4v*)pk;
        }
        if (wv < 12) {
            const float* cb = cond + (size_t)b * 80 * T_LEN + t0 + lane;
            unsigned pk[4];
#pragma unroll
            for (int e = 0; e < 4; ++e) {
                int c0 = wv * 8 + 2 * e, c1 = c0 + 1;
                float v0 = (c0 < 80) ? cb[(size_t)c0 * T_LEN] : ((c0 == 80) ? 1.f : 0.f);
                float v1 = (c1 < 80) ? cb[(size_t)c1 * T_LEN] : 0.f;
                pk[e] = cvtpk(v0, v1);
            }
            *(uint4v*)&sm[R_CND + (wv * 64 + lane) * 8] = *(uint4v*)pk;
        }
    }
    __syncthreads();

    // ---- input conv ----
    f32x4 hres[2] = {{0.f,0.f,0.f,0.f},{0.f,0.f,0.f,0.f}};
    {
        f32x4 acc[2] = {{0.f,0.f,0.f,0.f},{0.f,0.f,0.f,0.f}};
        singleN<4>((const short*)&sm[WB0], sm, tl8, 0, lg, awoff, acc);
        singleN<4>((const short*)&sm[WB1], sm, tl8, 4, lg, awoff, acc);
#pragma unroll
        for (int mt = 0; mt < 2; ++mt) {
            int cb0 = chA + mt * 16;
            f32x4 bv = {ib[cb0], ib[cb0 + 1], ib[cb0 + 2], ib[cb0 + 3]};
            hres[mt] = acc[mt] + bv;
        }
    }
    __syncthreads();                       // all waves done reading x slots 0..15
    {
        short* hrow = hbt + (size_t)b * SLAB + (size_t)(GUARD + tg) * 128 + chA;
#pragma unroll
        for (int mt = 0; mt < 2; ++mt) {
            uint2v hv = {cvtpk(hres[mt][0], hres[mt][1]), cvtpk(hres[mt][2], hres[mt][3])};
            stg8_sc1(hrow + mt * 16, hv);
            *(uint2v*)&sm[R_HT + ((kbA + mt * 2) * 64 + tl) * 8 + e0] = hv;
        }
    }
    __syncthreads();                       // drains stores (vmcnt 0)
    if (tid == 0) st_flag(&rdy[bidx], 1);

    f32x4 skp[2] = {{0.f,0.f,0.f,0.f},{0.f,0.f,0.f,0.f}};

    // ---- 30 layers ----
    for (int li = 0; li < NLAYER; ++li) {
        const int d   = 1 << (li % 10);
        const int ksh = (d + 63) >> 6;
        const short* wl  = wp + (size_t)li * LS;
        const short* hcb = hbt + (size_t)((li & 3) * 2 + b) * SLAB;
        short*       hnb = hbt + (size_t)(((li + 1) & 3) * 2 + b) * SLAB;

        stageW2(wl, (short*)&sm[WB0], wv, lane);                       // S0
        __syncthreads();                                               // barA: c0 ready
        if (lane == 0 && ti >= ksh) wait_ge(&rdy[bidx - ksh], li + 1);
        bf16x8 Bg[4];
        {
            const short* hr = hcb + (size_t)(GUARD + tg - d) * 128 + lg * 8;
#pragma unroll
            for (int ks = 0; ks < 4; ++ks) ldg16_sc1(&Bg[ks], hr + ks * 32);
        }
        stageW2(wl + C1, (short*)&sm[WB1], wv, lane);                  // S1
        f32x4 aa[2] = {{0.f,0.f,0.f,0.f},{0.f,0.f,0.f,0.f}};
        f32x4 ag[2] = {{0.f,0.f,0.f,0.f},{0.f,0.f,0.f,0.f}};
        pairN<2>((const short*)&sm[WB0], sm, R_HT + tl8, 0, lg, awoff, aa, ag);   // c0
        __syncthreads();                                               // barB: c1+Bg done
        if (tid == 0) st_flag(&dn[bidx], li + 1);
        stageW2(wl + C2, (short*)&sm[WB0], wv, lane);                  // S2
        pairN<2>((const short*)&sm[WB1], sm, R_HT + tl8, 2, lg, awoff, aa, ag);   // c1
        __syncthreads();                                               // barC
        stageW1(wl + C3, (short*)&sm[WB1], wv, lane);                  // S3 (half)
        pairN<2>((const short*)&sm[WB0], sm, R_CND + tl8, 0, lg, awoff, aa, ag);  // c2
        __syncthreads();                                               // barD
        stageW2(wl + C4, (short*)&sm[WB0], wv, lane);                  // S4
        pairN<1>((const short*)&sm[WB1], sm, R_CND + tl8, 2, lg, awoff, aa, ag);  // c3
        __syncthreads();                                               // barE
        stageW2(wl + C5, (short*)&sm[WB1], wv, lane);                  // S5
        {   // c4: d0 with global-B (Bg regs)
            const short* wb = (const short*)&sm[WB0];
#pragma unroll
            for (int ks = 0; ks < 4; ++ks) {
#pragma unroll
                for (int mt = 0; mt < 2; ++mt) {
                    bf16x8 a = *(const bf16x8*)&wb[ks * 4096 + awoff + mt * 512];
                    aa[mt] = mfma_(a, Bg[ks], aa[mt]);
                }
            }
        }
#pragma unroll
        for (int mt = 0; mt < 2; ++mt) {   // act -> R_OUT
            uint2v ov = {cvtpk(gated_act(aa[mt][0], ag[mt][0]), gated_act(aa[mt][1], ag[mt][1])),
                         cvtpk(gated_act(aa[mt][2], ag[mt][2]), gated_act(aa[mt][3], ag[mt][3]))};
            *(uint2v*)&sm[R_OUT + ((kbA + mt * 2) * 64 + tl) * 8 + e0] = ov;
        }
        __syncthreads();                                               // barF: S5 ready, R_OUT visible
        stageW2(wl + C6, (short*)&sm[WB0], wv, lane);                  // S6
        f32x4 ar[2]  = {{0.f,0.f,0.f,0.f},{0.f,0.f,0.f,0.f}};
        f32x4 as2[2] = {{0.f,0.f,0.f,0.f},{0.f,0.f,0.f,0.f}};
        pairN<2>((const short*)&sm[WB1], sm, R_OUT + tl8, 0, lg, awoff, ar, as2); // c5
        __syncthreads();                                               // barG: S6 ready
        pairN<2>((const short*)&sm[WB0], sm, R_OUT + tl8, 2, lg, awoff, ar, as2); // c6

        const float* rbl = rbias + li * 128 + chA;
        const float* sbl = sbias + li * 128 + chA;
#pragma unroll
        for (int mt = 0; mt < 2; ++mt) {
            f32x4 rbv = {rbl[mt*16], rbl[mt*16+1], rbl[mt*16+2], rbl[mt*16+3]};
            f32x4 sbv = {sbl[mt*16], sbl[mt*16+1], sbl[mt*16+2], sbl[mt*16+3]};
            skp[mt]  = skp[mt] + as2[mt] + sbv;
            hres[mt] = (hres[mt] + ar[mt] + rbv) * INV_SQRT2;
        }
        if (li < NLAYER - 1) {
            if (lane == 0 && li >= 3) {    // WAR vs readers of h^{li-3} (same slab)
                int d3 = 1 << ((li - 3) % 10);
                int k3 = (d3 + 63) >> 6;
                if (ti + k3 < NTPB) wait_ge(&dn[bidx + k3], li - 2);
            }
            short* hrow = hnb + (size_t)(GUARD + tg) * 128 + chA;
#pragma unroll
            for (int mt = 0; mt < 2; ++mt) {
                uint2v hv = {cvtpk(hres[mt][0], hres[mt][1]), cvtpk(hres[mt][2], hres[mt][3])};
                stg8_sc1(hrow + mt * 16, hv);
                *(uint2v*)&sm[R_HT + ((kbA + mt * 2) * 64 + tl) * 8 + e0] = hv;
            }
        }
        __syncthreads();                                               // barH: stores drained
        if (tid == 0 && li < NLAYER - 1) st_flag(&rdy[bidx], li + 2);
    }

    // ---- output head ----
#pragma unroll
    for (int mt = 0; mt < 2; ++mt) {       // skip -> R_HT
        uint2v sv = {cvtpk(skp[mt][0], skp[mt][1]), cvtpk(skp[mt][2], skp[mt][3])};
        *(uint2v*)&sm[R_HT + ((kbA + mt * 2) * 64 + tl) * 8 + e0] = sv;
    }
    stageW2(wp + OUT1_OFF, (short*)&sm[WB0], wv, lane);
    stageW2(wp + OUT2_OFF, (short*)&sm[WB1], wv, lane);
    __syncthreads();                       // skip visible; out1 + out2a ready
    f32x4 ay[2] = {{0.f,0.f,0.f,0.f},{0.f,0.f,0.f,0.f}};
    singleN<4>((const short*)&sm[WB0], sm, R_HT + tl8, 0, lg, awoff, ay);
#pragma unroll
    for (int mt = 0; mt < 2; ++mt) {       // y = relu(. + b1) -> R_OUT
        int cb0 = chA + mt * 16;
        float y0 = fmaxf(ay[mt][0] + b1[cb0],     0.f);
        float y1 = fmaxf(ay[mt][1] + b1[cb0 + 1], 0.f);
        float y2 = fmaxf(ay[mt][2] + b1[cb0 + 2], 0.f);
        float y3 = fmaxf(ay[mt][3] + b1[cb0 + 3], 0.f);
        uint2v yv = {cvtpk(y0, y1), cvtpk(y2, y3)};
        *(uint2v*)&sm[R_OUT + ((kbA + mt * 2) * 64 + tl) * 8 + e0] = yv;
    }
    __syncthreads();                       // y visible; WB0 free
    stageW2(wp + OUT2_OFF + 16384, (short*)&sm[WB0], wv, lane);
    f32x4 ao[4] = {{0.f,0.f,0.f,0.f},{0.f,0.f,0.f,0.f},
                   {0.f,0.f,0.f,0.f},{0.f,0.f,0.f,0.f}};
    {
        const short* wb = (const short*)&sm[WB1];
#pragma unroll
        for (int ksp = 0; ksp < 2; ++ksp) {
            bf16x8 B = *(const bf16x8*)&sm[R_OUT + tl8 + (ksp * 4 + lg) * 512];
#pragma unroll
            for (int mt = 0; mt < 4; ++mt) {
                int fg = 4 * wm + mt;
                bf16x8 A = *(const bf16x8*)&wb[(ksp * 2 + (fg >> 3)) * 4096 + (fg & 7) * 512 + lane8];
                ao[mt] = mfma_(A, B, ao[mt]);
            }
        }
    }
    __syncthreads();                       // out2b ready
    {
        const short* wb = (const short*)&sm[WB0];
#pragma unroll
        for (int ksp = 0; ksp < 2; ++ksp) {
            bf16x8 B = *(const bf16x8*)&sm[R_OUT + tl8 + ((2 + ksp) * 4 + lg) * 512];
#pragma unroll
            for (int mt = 0; mt < 4; ++mt) {
                int fg = 4 * wm + mt;
                bf16x8 A = *(const bf16x8*)&wb[(ksp * 2 + (fg >> 3)) * 4096 + (fg & 7) * 512 + lane8];
                ao[mt] = mfma_(A, B, ao[mt]);
            }
        }
    }
#pragma unroll
    for (int mt = 0; mt < 4; ++mt) {
        int ch2 = wm * 64 + mt * 16 + lg * 4;
        float* op = outp + ((size_t)(b * 256 + ch2)) * T_LEN + tg;
        op[0]         = ao[mt][0] + b2[ch2];
        op[T_LEN]     = ao[mt][1] + b2[ch2 + 1];
        op[2 * T_LEN] = ao[mt][2] + b2[ch2 + 2];
        op[3 * T_LEN] = ao[mt][3] + b2[ch2 + 3];
    }
}

extern "C" void kernel_launch(void* const* d_in, const int* in_sizes, int n_in,
                              void* d_out, int out_size, void* d_ws, size_t ws_size,
                              hipStream_t stream)
{
    const float* x       = (const float*)d_in[0];
    const float* cond    = (const float*)d_in[1];
    const float* input_w = (const float*)d_in[2];
    const float* input_b = (const float*)d_in[3];
    const float* dil_w   = (const float*)d_in[4];
    const float* dil_b   = (const float*)d_in[5];
    const float* gate_w  = (const float*)d_in[6];
    const float* gate_b  = (const float*)d_in[7];
    const float* cond_w  = (const float*)d_in[8];
    const float* cond_b  = (const float*)d_in[9];
    const float* condg_w = (const float*)d_in[10];
    const float* condg_b = (const float*)d_in[11];
    const float* res_w   = (const float*)d_in[12];
    const float* res_b   = (const float*)d_in[13];
    const float* skip_w  = (const float*)d_in[14];
    const float* skip_b  = (const float*)d_in[15];
    const float* out1_w  = (const float*)d_in[16];
    const float* out1_b  = (const float*)d_in[17];
    const float* out2_w  = (const float*)d_in[18];
    const float* out2_b  = (const float*)d_in[19];
    float* outp = (float*)d_out;

    short* wpk = (short*)d_ws;                         // 6400*512 shorts
    short* hbt = wpk + (size_t)6400 * 512;             // 8 slabs (4 levels x 2 batches)
    int*   flg = (int*)(hbt + (size_t)8 * SLAB);       // 512 ints
    int*   rdy = flg;
    int*   dn  = flg + 256;

    k_pack<<<1600, 256, 0, stream>>>(dil_w, gate_w, cond_w, condg_w, res_w, skip_w,
                                     input_w, out1_w, out2_w,
                                     dil_b, cond_b, gate_b, condg_b, wpk, hbt, flg);

    void* args[] = {(void*)&x, (void*)&cond, (void*)&wpk, (void*)&hbt,
                    (void*)&input_b, (void*)&res_b, (void*)&skip_b,
                    (void*)&out1_b, (void*)&out2_b, (void*)&outp,
                    (void*)&rdy, (void*)&dn};
    hipLaunchCooperativeKernel((void*)k_wavenet, dim3(NBLK), dim3(1024), args, 0, stream);
}